// Round 9
// baseline (203.160 us; speedup 1.0000x reference)
//
#include <hip/hip_runtime.h>

#define NN 49
#define D0 768
#define D1 256
#define D2 128

typedef short v8s __attribute__((ext_vector_type(8)));
typedef float v4f __attribute__((ext_vector_type(4)));
typedef int   v4i __attribute__((ext_vector_type(4)));

__device__ __forceinline__ unsigned short f2bf(float f) {
  unsigned int u = __float_as_uint(f);
  u += 0x7FFFu + ((u >> 16) & 1u);   // RNE; inputs finite
  return (unsigned short)(u >> 16);
}
__device__ __forceinline__ float bf2f(unsigned short u) {
  return __uint_as_float((unsigned)u << 16);
}

// bijective within each 32-wide k-block: packs lane-group q's 8 frag elems
// (k = 32s + 4q+i and 32s + 16 + 4q+i) into contiguous bytes [64s+16q, +16)
__device__ __forceinline__ int permk(int k) {
  return (k & ~31) | ((k & 12) << 1) | ((k & 16) >> 2) | (k & 3);
}

// GCN-normalized 7x7-grid adjacency entry (exact-zero outside stencil / pad)
__device__ __forceinline__ float ahat(int m, int k) {
  if (m >= NN || k >= NN) return 0.f;
  int ym = m / 7, xm = m % 7, yk = k / 7, xk = k % 7;
  int dy = ym - yk, dx = xm - xk;
  if (dy < -1 || dy > 1 || dx < -1 || dx > 1) return 0.f;
  float rm = rsqrtf((float)((1 + (ym > 0) + (ym < 6)) * (1 + (xm > 0) + (xm < 6))) + 1.0f);
  float rk = rsqrtf((float)((1 + (yk > 0) + (yk < 6)) * (1 + (xk > 0) + (xk < 6))) + 1.0f);
  return ((m == k) ? 2.0f : 1.0f) * rm * rk;
}

// ======================= setup: pre-convert weights ==========================
// Per-THREAD fragment images:
// W1: byte = (kc*2048 + p*256 + t)*16, p = 2*nt + s.  W2: p = 2*nt + s (nt<2).
#define W1_IMG_BYTES 393216
#define WS_NEEDED    458752

__global__ void prep_w(const float* __restrict__ W1, const float* __restrict__ W2,
                       char* __restrict__ wimg) {
  int id = blockIdx.x * 256 + threadIdx.x;
  if (id < 24576) {              // W1: (kc 12, p 8, t 256)
    int p = (id >> 8) & 7, tt = id & 255;
    int wvv = tt >> 6, lnn = tt & 63, qq = lnn >> 4, lmm = lnn & 15;
    int nt = p >> 1, s = p & 1;
    int n  = 64 * wvv + 16 * nt + lmm;
    int k0 = (id >> 11) * 64 + 32 * s + 4 * qq;
    v8s v;
    #pragma unroll
    for (int i = 0; i < 4; ++i) {
      v[i]     = (short)f2bf(W1[(size_t)(k0 + i) * D1 + n]);
      v[i + 4] = (short)f2bf(W1[(size_t)(k0 + 16 + i) * D1 + n]);
    }
    *(v8s*)(wimg + (size_t)id * 16) = v;
  }
  int id2 = id - 24576;
  if (id2 >= 0 && id2 < 4096) {  // W2: (kc 4, p 4, t 256)
    int p = (id2 >> 8) & 3, tt = id2 & 255;
    int wvv = tt >> 6, lnn = tt & 63, qq = lnn >> 4, lmm = lnn & 15;
    int nt = p >> 1, s = p & 1;
    int n  = 32 * wvv + 16 * nt + lmm;
    int k0 = (id2 >> 10) * 64 + 32 * s + 4 * qq;
    v8s v;
    #pragma unroll
    for (int i = 0; i < 4; ++i) {
      v[i]     = (short)f2bf(W2[(size_t)(k0 + i) * D2 + n]);
      v[i + 4] = (short)f2bf(W2[(size_t)(k0 + 16 + i) * D2 + n]);
    }
    *(v8s*)(wimg + W1_IMG_BYTES + (size_t)id2 * 16) = v;
  }
}

// ============================ main fused kernel ==============================
// 2 batches per block, batch-rotated phase pipeline. LDS: sX0 [0,8K) sX1
// [8K,16K) | sH1_0 [16K,48K) | sH1_1 [48K,80K). spool overlays dead sX. 80KB.
#define SX0    0
#define SX1    8192
#define SH1_0  16384
#define SH1_1  49152
#define SPOOL0 0
#define SPOOL1 512
#define NSMEM7 81920

__device__ __forceinline__ void ldw8(v8s* dst, const char* base) {
  #pragma unroll
  for (int p = 0; p < 8; ++p) dst[p] = *(const v8s*)(base + p * 4096);
}
__device__ __forceinline__ void ldw4(v8s* dst, const char* base) {
  #pragma unroll
  for (int p = 0; p < 4; ++p) dst[p] = *(const v8s*)(base + p * 4096);
}
__device__ __forceinline__ void commit8(char* lds, const float4& a, const float4& b) {
  v8s v;
  v[0] = (short)f2bf(a.x); v[1] = (short)f2bf(a.y);
  v[2] = (short)f2bf(a.z); v[3] = (short)f2bf(a.w);
  v[4] = (short)f2bf(b.x); v[5] = (short)f2bf(b.y);
  v[6] = (short)f2bf(b.z); v[7] = (short)f2bf(b.w);
  *(v8s*)lds = v;
}
#define PHASE_END  do {                                        \
    __builtin_amdgcn_sched_barrier(0);                         \
    asm volatile("s_waitcnt lgkmcnt(0)" ::: "memory");         \
    __builtin_amdgcn_s_barrier();                              \
    __builtin_amdgcn_sched_barrier(0);                         \
  } while (0)

__global__ __launch_bounds__(256, 2) void gcn_fused9(
    const float* __restrict__ X, const char* __restrict__ wimg,
    const float* __restrict__ b1v, const float* __restrict__ b2v,
    const float* __restrict__ fcWv, const float* __restrict__ fcbv,
    float* __restrict__ out)
{
  __shared__ __align__(16) char smem[NSMEM7];
  const int t  = threadIdx.x;
  const int wv = t >> 6;
  const int ln = t & 63;
  const int q  = ln >> 4;
  const int lm = ln & 15;

  // zero pad rows 49-63 of both X buffers (once)
  if (t < 240) {
    int i = (t >= 120) ? t - 120 : t;
    int base = ((t >= 120) ? SX1 : SX0) + 6272 + i * 16;
    *(v4i*)(smem + base) = (v4i){0, 0, 0, 0};
  }

  // -------- X staging: 784 segments (2 batches x 49 rows x 8 frags) --------
  // A-set (sX0): p0 = seg t (b0 rows 0-31); p1 if t<136 (b0 rows 32-48)
  // B-set (sX1): p1 if t>=136 (b1 rows 0-14); p2 = seg t+120 (b1 rows 15-46);
  //              p3 if t<16 (b1 rows 47-48)
  const float* X0 = X + (size_t)(2 * blockIdx.x) * (NN * D0);
  const float* X1 = X0 + NN * D0;

  const int g1 = t + 256;
  const int b1g = (g1 >= 392) ? 1 : 0;      // 1 iff t >= 136 (p1 in B-set)
  const bool act3 = (t < 16);
  const int s0 = t, s1 = g1 - 392 * b1g, s2 = t + 120, s3 = t + 376;
  const int r0 = s0 >> 3, f0 = s0 & 7;
  const int r1 = s1 >> 3, f1 = s1 & 7;
  const int r2 = s2 >> 3, f2 = s2 & 7;
  const int r3 = s3 >> 3, f3 = s3 & 7;
  const float* base0 = X0 + r0 * D0 + 32 * (f0 >> 2) + 4 * (f0 & 3);
  const float* base1 = (b1g ? X1 : X0) + r1 * D0 + 32 * (f1 >> 2) + 4 * (f1 & 3);
  const float* base2 = X1 + r2 * D0 + 32 * (f2 >> 2) + 4 * (f2 & 3);
  const float* base3_ = X1 + r3 * D0 + 32 * (f3 >> 2) + 4 * (f3 & 3);
  const float* base3 = act3 ? base3_ : base0;     // dummy in-bounds when idle
  const int lds0 = SX0 + ((r0 * 128 + 16 * f0) ^ ((r0 & 7) << 4));
  const int lds1 = (b1g ? SX1 : SX0) + ((r1 * 128 + 16 * f1) ^ ((r1 & 7) << 4));
  const int lds2 = SX1 + ((r2 * 128 + 16 * f2) ^ ((r2 & 7) << 4));
  const int lds3 = SX1 + (((r3 & 63) * 128 + 16 * f3) ^ ((r3 & 7) << 4));

  const int tofs = t * 16;

  v4f accA[4][4], accB[4][4];
  #pragma unroll
  for (int i = 0; i < 4; ++i)
    #pragma unroll
    for (int j = 0; j < 4; ++j) {
      accA[i][j] = (v4f){0.f, 0.f, 0.f, 0.f};
      accB[i][j] = (v4f){0.f, 0.f, 0.f, 0.f};
    }

  // prologue: W chunk0; X chunk0 (all sets); commit A-set(0); issue A-set(1)
  v8s wA[8];
  ldw8(wA, wimg + tofs);
  float4 p0a = *(const float4*)(base0);
  float4 p0b = *(const float4*)(base0 + 16);
  float4 p1a = *(const float4*)(base1);
  float4 p1b = *(const float4*)(base1 + 16);
  float4 p2a = *(const float4*)(base2);
  float4 p2b = *(const float4*)(base2 + 16);
  float4 p3a = *(const float4*)(base3);
  float4 p3b = *(const float4*)(base3 + 16);

  commit8((char*)smem + lds0, p0a, p0b);
  if (!b1g) commit8((char*)smem + lds1, p1a, p1b);
  {
    p0a = *(const float4*)(base0 + 64);
    p0b = *(const float4*)(base0 + 64 + 16);
    if (!b1g) {
      p1a = *(const float4*)(base1 + 64);
      p1b = *(const float4*)(base1 + 64 + 16);
    }
  }
  PHASE_END;

  for (int kc = 0; kc < 12; ++kc) {
    // ---- phase A: MFMA batch0 on sX0(kc) || commit sX1(kc) || issue B-set(kc+1)
    #pragma unroll
    for (int ks = 0; ks < 2; ++ks) {
      const int off = ks * 64 + (q << 4);
      v8s af[4];
      #pragma unroll
      for (int mt = 0; mt < 4; ++mt) {
        int row = mt * 16 + lm;
        af[mt] = *(const v8s*)(smem + SX0 + ((row * 128 + off) ^ ((row & 7) << 4)));
      }
      #pragma unroll
      for (int mt = 0; mt < 4; ++mt)
        #pragma unroll
        for (int nt = 0; nt < 4; ++nt)
          accA[mt][nt] = __builtin_amdgcn_mfma_f32_16x16x32_bf16(af[mt], wA[2 * nt + ks], accA[mt][nt], 0, 0, 0);
    }
    if (b1g) commit8((char*)smem + lds1, p1a, p1b);
    commit8((char*)smem + lds2, p2a, p2b);
    if (act3) commit8((char*)smem + lds3, p3a, p3b);
    if (kc < 11) {
      const int o = (kc + 1) * 64;
      if (b1g) {
        p1a = *(const float4*)(base1 + o);
        p1b = *(const float4*)(base1 + o + 16);
      }
      p2a = *(const float4*)(base2 + o);
      p2b = *(const float4*)(base2 + o + 16);
      if (act3) {
        p3a = *(const float4*)(base3 + o);
        p3b = *(const float4*)(base3 + o + 16);
      }
    }
    PHASE_END;

    // ---- phase B: MFMA batch1 on sX1(kc) || commit sX0(kc+1) || issue A-set(kc+2)
    #pragma unroll
    for (int ks = 0; ks < 2; ++ks) {
      const int off = ks * 64 + (q << 4);
      v8s af[4];
      #pragma unroll
      for (int mt = 0; mt < 4; ++mt) {
        int row = mt * 16 + lm;
        af[mt] = *(const v8s*)(smem + SX1 + ((row * 128 + off) ^ ((row & 7) << 4)));
      }
      #pragma unroll
      for (int mt = 0; mt < 4; ++mt)
        #pragma unroll
        for (int nt = 0; nt < 4; ++nt)
          accB[mt][nt] = __builtin_amdgcn_mfma_f32_16x16x32_bf16(af[mt], wA[2 * nt + ks], accB[mt][nt], 0, 0, 0);
    }
    if (kc < 11) {
      commit8((char*)smem + lds0, p0a, p0b);
      if (!b1g) commit8((char*)smem + lds1, p1a, p1b);
      if (kc < 10) {
        const int o = (kc + 2) * 64;
        p0a = *(const float4*)(base0 + o);
        p0b = *(const float4*)(base0 + o + 16);
        if (!b1g) {
          p1a = *(const float4*)(base1 + o);
          p1b = *(const float4*)(base1 + o + 16);
        }
      }
      ldw8(wA, wimg + (kc + 1) * 32768 + tofs);   // reload W after last use
      PHASE_END;
    }
  }

  // -------- pack C1 accumulators to bf16 b-frags (halves reg footprint) --------
  v8s bA[2][4], bB[2][4];
  #pragma unroll
  for (int s2 = 0; s2 < 2; ++s2)
    #pragma unroll
    for (int nt = 0; nt < 4; ++nt) {
      v8s a, b;
      #pragma unroll
      for (int i = 0; i < 4; ++i) {
        a[i]     = (short)f2bf(accA[2 * s2][nt][i]);
        a[i + 4] = (short)f2bf(accA[2 * s2 + 1][nt][i]);
        b[i]     = (short)f2bf(accB[2 * s2][nt][i]);
        b[i + 4] = (short)f2bf(accB[2 * s2 + 1][nt][i]);
      }
      bA[s2][nt] = a; bB[s2][nt] = b;
    }

  float bi[4];
  #pragma unroll
  for (int nt = 0; nt < 4; ++nt) bi[nt] = b1v[64 * wv + 16 * nt + lm];

  // Ahat fragments, hi + lo split (shared by both batches and both AGGs)
  v8s afH[4][2], afL[4][2];
  #pragma unroll
  for (int mt = 0; mt < 4; ++mt) {
    int m = 16 * mt + lm;
    #pragma unroll
    for (int s2 = 0; s2 < 2; ++s2) {
      v8s hi, lo;
      #pragma unroll
      for (int j = 0; j < 8; ++j) {
        int k = 32 * s2 + ((j & 4) << 2) + 4 * q + (j & 3);
        float v = ahat(m, k);
        unsigned short h = f2bf(v);
        hi[j] = (short)h;
        lo[j] = (short)f2bf(v - bf2f(h));
      }
      afH[mt][s2] = hi; afL[mt][s2] = lo;
    }
  }

  // ====== AGG1 per batch: H1 = relu(Ahat @ C1 + b1) -> sH1_b ======
  #pragma unroll
  for (int bb = 0; bb < 2; ++bb) {
    v4f ag[4][4];
    #pragma unroll
    for (int mt = 0; mt < 4; ++mt)
      #pragma unroll
      for (int nt = 0; nt < 4; ++nt)
        ag[mt][nt] = (v4f){bi[nt], bi[nt], bi[nt], bi[nt]};
    #pragma unroll
    for (int s2 = 0; s2 < 2; ++s2)
      #pragma unroll
      for (int nt = 0; nt < 4; ++nt) {
        v8s b = (bb == 0) ? bA[s2][nt] : bB[s2][nt];
        #pragma unroll
        for (int mt = 0; mt < 4; ++mt) {
          ag[mt][nt] = __builtin_amdgcn_mfma_f32_16x16x32_bf16(afL[mt][s2], b, ag[mt][nt], 0, 0, 0);
          ag[mt][nt] = __builtin_amdgcn_mfma_f32_16x16x32_bf16(afH[mt][s2], b, ag[mt][nt], 0, 0, 0);
        }
      }
    const int hbase = (bb == 0) ? SH1_0 : SH1_1;
    #pragma unroll
    for (int mt = 0; mt < 4; ++mt)
      #pragma unroll
      for (int nt = 0; nt < 4; ++nt) {
        int ch  = 64 * wv + 16 * nt + lm;
        int chb = 2 * permk(ch);
        #pragma unroll
        for (int r = 0; r < 4; ++r) {
          int row = 16 * mt + 4 * q + r;
          float hv = fmaxf(ag[mt][nt][r], 0.f);
          int byte = (row * 512 + chb) ^ ((row & 7) << 4);
          *(unsigned short*)(smem + hbase + byte) = f2bf(hv);
        }
      }
  }

  // issue W2 loads now (L2 latency hides under the barrier)
  const char* w2img = wimg + W1_IMG_BYTES;
  v8s w2c0[4], w2c1[4], w2c2[4], w2c3[4];
  ldw4(w2c0, w2img + tofs);
  ldw4(w2c1, w2img + 16384 + tofs);
  ldw4(w2c2, w2img + 2 * 16384 + tofs);
  ldw4(w2c3, w2img + 3 * 16384 + tofs);

  PHASE_END;

  // ====== GEMM2 + AGG2 + pool per batch (w2c shared, no barriers) ======
  float b2i0 = b2v[32 * wv + lm];
  float b2i1 = b2v[32 * wv + 16 + lm];

  #pragma unroll
  for (int bb = 0; bb < 2; ++bb) {
    const int hbase = (bb == 0) ? SH1_0 : SH1_1;
    v4f acc3[4][2];
    #pragma unroll
    for (int i = 0; i < 4; ++i) {
      acc3[i][0] = (v4f){0.f, 0.f, 0.f, 0.f};
      acc3[i][1] = (v4f){0.f, 0.f, 0.f, 0.f};
    }
    #pragma unroll
    for (int kc = 0; kc < 4; ++kc)
      #pragma unroll
      for (int ks = 0; ks < 2; ++ks) {
        const int off = ks * 64 + (q << 4);
        v8s af[4];
        #pragma unroll
        for (int mt = 0; mt < 4; ++mt) {
          int row = mt * 16 + lm;
          int byte = (row * 512 + kc * 128 + off) ^ ((row & 7) << 4);
          af[mt] = *(const v8s*)(smem + hbase + byte);
        }
        const v8s* wc = (kc == 0) ? w2c0 : (kc == 1) ? w2c1 : (kc == 2) ? w2c2 : w2c3;
        #pragma unroll
        for (int mt = 0; mt < 4; ++mt)
          #pragma unroll
          for (int nt = 0; nt < 2; ++nt)
            acc3[mt][nt] = __builtin_amdgcn_mfma_f32_16x16x32_bf16(af[mt], wc[2 * nt + ks], acc3[mt][nt], 0, 0, 0);
      }
    // AGG2
    v4f a2[4][2];
    #pragma unroll
    for (int mt = 0; mt < 4; ++mt) {
      a2[mt][0] = (v4f){b2i0, b2i0, b2i0, b2i0};
      a2[mt][1] = (v4f){b2i1, b2i1, b2i1, b2i1};
    }
    #pragma unroll
    for (int s2 = 0; s2 < 2; ++s2)
      #pragma unroll
      for (int nt = 0; nt < 2; ++nt) {
        v8s b;
        #pragma unroll
        for (int i = 0; i < 4; ++i) {
          b[i]     = (short)f2bf(acc3[2 * s2][nt][i]);
          b[i + 4] = (short)f2bf(acc3[2 * s2 + 1][nt][i]);
        }
        #pragma unroll
        for (int mt = 0; mt < 4; ++mt) {
          a2[mt][nt] = __builtin_amdgcn_mfma_f32_16x16x32_bf16(afL[mt][s2], b, a2[mt][nt], 0, 0, 0);
          a2[mt][nt] = __builtin_amdgcn_mfma_f32_16x16x32_bf16(afH[mt][s2], b, a2[mt][nt], 0, 0, 0);
        }
      }
    // pool: rows 0..47 (mt<3) + row 48 (q==0, r==0)
    float ps0 = 0.f, ps1 = 0.f;
    #pragma unroll
    for (int mt = 0; mt < 3; ++mt)
      #pragma unroll
      for (int r = 0; r < 4; ++r) {
        ps0 += fmaxf(a2[mt][0][r], 0.f);
        ps1 += fmaxf(a2[mt][1][r], 0.f);
      }
    if (q == 0) {
      ps0 += fmaxf(a2[3][0][0], 0.f);
      ps1 += fmaxf(a2[3][1][0], 0.f);
    }
    ps0 += __shfl_xor(ps0, 16); ps0 += __shfl_xor(ps0, 32);
    ps1 += __shfl_xor(ps1, 16); ps1 += __shfl_xor(ps1, 32);
    float* spool = (float*)(smem + ((bb == 0) ? SPOOL0 : SPOOL1));
    if (q == 0) {
      spool[32 * wv + lm]      = ps0 * (1.0f / 49.0f);
      spool[32 * wv + 16 + lm] = ps1 * (1.0f / 49.0f);
    }
  }
  __syncthreads();
  if (t < 8) {
    int bb = t >> 2, c = t & 3;
    const float* spool = (const float*)(smem + ((bb == 0) ? SPOOL0 : SPOOL1));
    float a = fcbv[c];
    for (int d = 0; d < D2; ++d) a += spool[d] * fcWv[d * 4 + c];
    out[(size_t)(2 * blockIdx.x + bb) * 4 + c] = a;
  }
}

// ===================== fallback (round-1 kernel, no d_ws) =====================
#define OFF_SX    0
#define OFF_SWT   8192
#define OFF_SC    0
#define OFF_SWT2  0
#define OFF_SPOOL 25872
#define OFF_SPF   30096
#define OFF_SH1   40960
#define OFF_NBRW  73728
#define OFF_NBRI  75492
#define OFF_B1    77256
#define OFF_B2    78280
#define OFF_FCW   78792
#define OFF_FCB   80840
#define SMEM_SZ   80856

__global__ __launch_bounds__(256, 2) void gcn_fused_fb(
    const float* __restrict__ X, const float* __restrict__ W1,
    const float* __restrict__ b1v, const float* __restrict__ W2,
    const float* __restrict__ b2v, const float* __restrict__ fcWv,
    const float* __restrict__ fcbv, float* __restrict__ out)
{
  __shared__ __align__(16) char smem[SMEM_SZ];
  const int t  = threadIdx.x;
  const int wv = t >> 6;
  const int ln = t & 63;
  const int q  = ln >> 4;
  const int lm = ln & 15;

  float* nbrW = (float*)(smem + OFF_NBRW);
  int*   nbrI = (int*)  (smem + OFF_NBRI);
  float* b1s  = (float*)(smem + OFF_B1);
  float* b2s  = (float*)(smem + OFF_B2);
  float* fcWs = (float*)(smem + OFF_FCW);
  float* fcbs = (float*)(smem + OFF_FCB);
  float* sC   = (float*)(smem + OFF_SC);

  if (t < D1) b1s[t] = b1v[t];
  if (t < D2) b2s[t] = b2v[t];
  fcWs[t]       = fcWv[t];
  fcWs[t + 256] = fcWv[t + 256];
  if (t < 4) fcbs[t] = fcbv[t];
  if (t < NN) {
    int y = t / 7, x = t % 7;
    float rm = rsqrtf((float)((1 + (y > 0) + (y < 6)) * (1 + (x > 0) + (x < 6))) + 1.0f);
    int cnt = 0;
    for (int dy = -1; dy <= 1; ++dy)
      for (int dx = -1; dx <= 1; ++dx) {
        int ny = y + dy, nx = x + dx;
        if (ny >= 0 && ny < 7 && nx >= 0 && nx < 7) {
          int n = ny * 7 + nx;
          float rn = rsqrtf((float)((1 + (ny > 0) + (ny < 6)) * (1 + (nx > 0) + (nx < 6))) + 1.0f);
          nbrW[t * 9 + cnt] = ((n == t) ? 2.0f : 1.0f) * rm * rn;
          nbrI[t * 9 + cnt] = n;
          ++cnt;
        }
      }
    for (; cnt < 9; ++cnt) { nbrW[t * 9 + cnt] = 0.0f; nbrI[t * 9 + cnt] = 0; }
  }
  __syncthreads();

  const float* Xb = X + (size_t)blockIdx.x * (NN * D0);
  v4f acc[4][4];
  #pragma unroll
  for (int i = 0; i < 4; ++i)
    #pragma unroll
    for (int j = 0; j < 4; ++j)
      acc[i][j] = (v4f){0.f, 0.f, 0.f, 0.f};

  for (int kc = 0; kc < 12; ++kc) {
    __syncthreads();
    #pragma unroll
    for (int p = 0; p < 4; ++p) {
      int idx = t + 256 * p;
      int row = idx >> 4;
      int k4  = (idx & 15) << 2;
      float4 v = {0.f, 0.f, 0.f, 0.f};
      if (row < NN) v = *(const float4*)(Xb + row * D0 + kc * 64 + k4);
      ushort4 s;
      s.x = f2bf(v.x); s.y = f2bf(v.y); s.z = f2bf(v.z); s.w = f2bf(v.w);
      int byte = row * 128 + 2 * permk(k4);
      byte ^= (row & 7) << 4;
      *(ushort4*)(smem + OFF_SX + byte) = s;
    }
    #pragma unroll
    for (int p = 0; p < 4; ++p) {
      int bid2 = t + 256 * p;
      int k0 = (bid2 & 15) << 2;
      int n0 = (bid2 >> 4) << 2;
      const float* wp = W1 + (size_t)(kc * 64 + k0) * D1 + n0;
      float4 r0 = *(const float4*)(wp);
      float4 r1 = *(const float4*)(wp + D1);
      float4 r2 = *(const float4*)(wp + 2 * D1);
      float4 r3 = *(const float4*)(wp + 3 * D1);
      int kb = 2 * permk(k0);
      ushort4 s; int byte;
      s.x = f2bf(r0.x); s.y = f2bf(r1.x); s.z = f2bf(r2.x); s.w = f2bf(r3.x);
      byte = (n0 + 0) * 128 + kb; byte ^= ((n0 + 0) & 7) << 4;
      *(ushort4*)(smem + OFF_SWT + byte) = s;
      s.x = f2bf(r0.y); s.y = f2bf(r1.y); s.z = f2bf(r2.y); s.w = f2bf(r3.y);
      byte = (n0 + 1) * 128 + kb; byte ^= ((n0 + 1) & 7) << 4;
      *(ushort4*)(smem + OFF_SWT + byte) = s;
      s.x = f2bf(r0.z); s.y = f2bf(r1.z); s.z = f2bf(r2.z); s.w = f2bf(r3.z);
      byte = (n0 + 2) * 128 + kb; byte ^= ((n0 + 2) & 7) << 4;
      *(ushort4*)(smem + OFF_SWT + byte) = s;
      s.x = f2bf(r0.w); s.y = f2bf(r1.w); s.z = f2bf(r2.w); s.w = f2bf(r3.w);
      byte = (n0 + 3) * 128 + kb; byte ^= ((n0 + 3) & 7) << 4;
      *(ushort4*)(smem + OFF_SWT + byte) = s;
    }
    __syncthreads();
    #pragma unroll
    for (int ks = 0; ks < 2; ++ks) {
      int off = ks * 64 + (q << 4);
      v8s af[4], bf[4];
      #pragma unroll
      for (int mt = 0; mt < 4; ++mt) {
        int row = mt * 16 + lm;
        int byte = row * 128 + off; byte ^= (row & 7) << 4;
        af[mt] = *(const v8s*)(smem + OFF_SX + byte);
      }
      #pragma unroll
      for (int nt = 0; nt < 4; ++nt) {
        int n = (wv * 4 + nt) * 16 + lm;
        int byte = n * 128 + off; byte ^= (n & 7) << 4;
        bf[nt] = *(const v8s*)(smem + OFF_SWT + byte);
      }
      #pragma unroll
      for (int mt = 0; mt < 4; ++mt)
        #pragma unroll
        for (int nt = 0; nt < 4; ++nt)
          acc[mt][nt] = __builtin_amdgcn_mfma_f32_16x16x32_bf16(af[mt], bf[nt], acc[mt][nt], 0, 0, 0);
    }
  }

  #pragma unroll
  for (int h = 0; h < 2; ++h) {
    __syncthreads();
    if ((wv >> 1) == h) {
      #pragma unroll
      for (int mt = 0; mt < 4; ++mt) {
        int rbase = mt * 16 + (q << 2);
        #pragma unroll
        for (int nt = 0; nt < 4; ++nt) {
          int c = ((wv & 1) * 4 + nt) * 16 + lm;
          #pragma unroll
          for (int r = 0; r < 4; ++r) {
            int row = rbase + r;
            if (row < NN) sC[row * 132 + c] = acc[mt][nt][r];
          }
        }
      }
    }
    __syncthreads();
    for (int p = 0; p < 7; ++p) {
      int idx = t + 256 * p;
      if (idx < NN * 32) {
        int m  = idx >> 5;
        int d4 = (idx & 31) << 2;
        int dg = h * 128 + d4;
        float a0 = b1s[dg], a1 = b1s[dg + 1], a2 = b1s[dg + 2], a3 = b1s[dg + 3];
        #pragma unroll
        for (int e = 0; e < 9; ++e) {
          float w = nbrW[m * 9 + e];
          int   n = nbrI[m * 9 + e];
          float4 cv = *(const float4*)(sC + n * 132 + d4);
          a0 += w * cv.x; a1 += w * cv.y; a2 += w * cv.z; a3 += w * cv.w;
        }
        a0 = fmaxf(a0, 0.f); a1 = fmaxf(a1, 0.f); a2 = fmaxf(a2, 0.f); a3 = fmaxf(a3, 0.f);
        ushort4 s; s.x = f2bf(a0); s.y = f2bf(a1); s.z = f2bf(a2); s.w = f2bf(a3);
        int byte = m * 512 + 2 * permk(dg);
        byte ^= (m & 7) << 4;
        *(ushort4*)(smem + OFF_SH1 + byte) = s;
      }
    }
  }

  v4f acc2[4][2];
  #pragma unroll
  for (int i = 0; i < 4; ++i) { acc2[i][0] = (v4f){0.f,0.f,0.f,0.f}; acc2[i][1] = (v4f){0.f,0.f,0.f,0.f}; }

  for (int kc = 0; kc < 4; ++kc) {
    __syncthreads();
    #pragma unroll
    for (int p = 0; p < 2; ++p) {
      int bid2 = t + 256 * p;
      int k0 = (bid2 & 15) << 2;
      int n0 = (bid2 >> 4) << 2;
      const float* wp = W2 + (size_t)(kc * 64 + k0) * D2 + n0;
      float4 r0 = *(const float4*)(wp);
      float4 r1 = *(const float4*)(wp + D2);
      float4 r2 = *(const float4*)(wp + 2 * D2);
      float4 r3 = *(const float4*)(wp + 3 * D2);
      int kb = 2 * permk(k0);
      ushort4 s; int byte;
      s.x = f2bf(r0.x); s.y = f2bf(r1.x); s.z = f2bf(r2.x); s.w = f2bf(r3.x);
      byte = (n0 + 0) * 128 + kb; byte ^= ((n0 + 0) & 7) << 4;
      *(ushort4*)(smem + OFF_SWT2 + byte) = s;
      s.x = f2bf(r0.y); s.y = f2bf(r1.y); s.z = f2bf(r2.y); s.w = f2bf(r3.y);
      byte = (n0 + 1) * 128 + kb; byte ^= ((n0 + 1) & 7) << 4;
      *(ushort4*)(smem + OFF_SWT2 + byte) = s;
      s.x = f2bf(r0.z); s.y = f2bf(r1.z); s.z = f2bf(r2.z); s.w = f2bf(r3.z);
      byte = (n0 + 2) * 128 + kb; byte ^= ((n0 + 2) & 7) << 4;
      *(ushort4*)(smem + OFF_SWT2 + byte) = s;
      s.x = f2bf(r0.w); s.y = f2bf(r1.w); s.z = f2bf(r2.w); s.w = f2bf(r3.w);
      byte = (n0 + 3) * 128 + kb; byte ^= ((n0 + 3) & 7) << 4;
      *(ushort4*)(smem + OFF_SWT2 + byte) = s;
    }
    __syncthreads();
    #pragma unroll
    for (int ks = 0; ks < 2; ++ks) {
      int off = ks * 64 + (q << 4);
      v8s af[4], bf2[2];
      #pragma unroll
      for (int mt = 0; mt < 4; ++mt) {
        int row = mt * 16 + lm;
        int byte = row * 512 + kc * 128 + off; byte ^= (row & 7) << 4;
        af[mt] = *(const v8s*)(smem + OFF_SH1 + byte);
      }
      #pragma unroll
      for (int nt = 0; nt < 2; ++nt) {
        int n = (wv * 2 + nt) * 16 + lm;
        int byte = n * 128 + off; byte ^= (n & 7) << 4;
        bf2[nt] = *(const v8s*)(smem + OFF_SWT2 + byte);
      }
      #pragma unroll
      for (int mt = 0; mt < 4; ++mt)
        #pragma unroll
        for (int nt = 0; nt < 2; ++nt)
          acc2[mt][nt] = __builtin_amdgcn_mfma_f32_16x16x32_bf16(af[mt], bf2[nt], acc2[mt][nt], 0, 0, 0);
    }
  }

  __syncthreads();
  #pragma unroll
  for (int mt = 0; mt < 4; ++mt) {
    int rbase = mt * 16 + (q << 2);
    #pragma unroll
    for (int nt = 0; nt < 2; ++nt) {
      int c = (wv * 2 + nt) * 16 + lm;
      #pragma unroll
      for (int r = 0; r < 4; ++r) {
        int row = rbase + r;
        if (row < NN) sC[row * 132 + c] = acc2[mt][nt][r];
      }
    }
  }
  __syncthreads();
  {
    int d4 = (t & 31) << 2;
    int g  = t >> 5;
    float p0 = 0.f, p1 = 0.f, p2 = 0.f, p3 = 0.f;
    int m0 = g * 7, m1 = (g * 7 + 7 < NN) ? (g * 7 + 7) : NN;
    for (int m = m0; m < m1; ++m) {
      float a0 = b2s[d4], a1 = b2s[d4 + 1], a2 = b2s[d4 + 2], a3 = b2s[d4 + 3];
      #pragma unroll
      for (int e = 0; e < 9; ++e) {
        float w = nbrW[m * 9 + e];
        int   n = nbrI[m * 9 + e];
        float4 cv = *(const float4*)(sC + n * 132 + d4);
        a0 += w * cv.x; a1 += w * cv.y; a2 += w * cv.z; a3 += w * cv.w;
      }
      p0 += fmaxf(a0, 0.f); p1 += fmaxf(a1, 0.f); p2 += fmaxf(a2, 0.f); p3 += fmaxf(a3, 0.f);
    }
    float* sp = (float*)(smem + OFF_SPOOL) + g * 132 + d4;
    sp[0] = p0; sp[1] = p1; sp[2] = p2; sp[3] = p3;
  }
  __syncthreads();
  if (t < D2) {
    const float* sp = (const float*)(smem + OFF_SPOOL);
    float s = 0.f;
    #pragma unroll
    for (int g = 0; g < 8; ++g) s += sp[g * 132 + t];
    ((float*)(smem + OFF_SPF))[t] = s * (1.0f / 49.0f);
  }
  __syncthreads();
  if (t < 4) {
    const float* pf = (const float*)(smem + OFF_SPF);
    float a = fcbs[t];
    for (int d = 0; d < D2; ++d) a += pf[d] * fcWs[d * 4 + t];
    out[(size_t)blockIdx.x * 4 + t] = a;
  }
}

extern "C" void kernel_launch(void* const* d_in, const int* in_sizes, int n_in,
                              void* d_out, int out_size, void* d_ws, size_t ws_size,
                              hipStream_t stream) {
  const float* X   = (const float*)d_in[0];
  const float* W1  = (const float*)d_in[1];
  const float* b1  = (const float*)d_in[2];
  const float* W2  = (const float*)d_in[3];
  const float* b2  = (const float*)d_in[4];
  const float* fcW = (const float*)d_in[5];
  const float* fcb = (const float*)d_in[6];
  float* out = (float*)d_out;
  int B = in_sizes[0] / (NN * D0);   // 4096
  if (d_ws != nullptr && ws_size >= (size_t)WS_NEEDED && (B % 2) == 0) {
    prep_w<<<112, 256, 0, stream>>>(W1, W2, (char*)d_ws);
    gcn_fused9<<<B / 2, 256, 0, stream>>>(X, (const char*)d_ws, b1, b2, fcW, fcb, out);
  } else {
    gcn_fused_fb<<<B, 256, 0, stream>>>(X, W1, b1, W2, b2, fcW, fcb, out);
  }
}

// Round 10
// 182.935 us; speedup vs baseline: 1.1106x; 1.1106x over previous
//
#include <hip/hip_runtime.h>

#define NN 49
#define D0 768
#define D1 256
#define D2 128

typedef short v8s __attribute__((ext_vector_type(8)));
typedef float v4f __attribute__((ext_vector_type(4)));
typedef int   v4i __attribute__((ext_vector_type(4)));

__device__ __forceinline__ unsigned short f2bf(float f) {
  unsigned int u = __float_as_uint(f);
  u += 0x7FFFu + ((u >> 16) & 1u);   // RNE; inputs finite
  return (unsigned short)(u >> 16);
}
__device__ __forceinline__ float bf2f(unsigned short u) {
  return __uint_as_float((unsigned)u << 16);
}

// bijective within each 32-wide k-block: packs lane-group q's 8 frag elems
// (k = 32s + 4q+i and 32s + 16 + 4q+i) into contiguous bytes [64s+16q, +16)
__device__ __forceinline__ int permk(int k) {
  return (k & ~31) | ((k & 12) << 1) | ((k & 16) >> 2) | (k & 3);
}

// GCN-normalized 7x7-grid adjacency entry (exact-zero outside stencil / pad)
__device__ __forceinline__ float ahat(int m, int k) {
  if (m >= NN || k >= NN) return 0.f;
  int ym = m / 7, xm = m % 7, yk = k / 7, xk = k % 7;
  int dy = ym - yk, dx = xm - xk;
  if (dy < -1 || dy > 1 || dx < -1 || dx > 1) return 0.f;
  float rm = rsqrtf((float)((1 + (ym > 0) + (ym < 6)) * (1 + (xm > 0) + (xm < 6))) + 1.0f);
  float rk = rsqrtf((float)((1 + (yk > 0) + (yk < 6)) * (1 + (xk > 0) + (xk < 6))) + 1.0f);
  return ((m == k) ? 2.0f : 1.0f) * rm * rk;
}

// ======================= setup: pre-convert weights ==========================
// Per-THREAD fragment images:
// W1: byte = (kc*2048 + p*256 + t)*16, p = 2*nt + s.  W2: p = 2*nt + s (nt<2).
// AH: Ahat hi/lo fragments, entry ((mt*2+s2)*256 + t)*16; hi then lo (32KB each).
#define W1_IMG_BYTES 393216
#define AH_OFF       458752
#define WS_NEEDED    524288

__global__ void prep_w(const float* __restrict__ W1, const float* __restrict__ W2,
                       char* __restrict__ wimg) {
  int id = blockIdx.x * 256 + threadIdx.x;
  if (id < 24576) {              // W1: (kc 12, p 8, t 256)
    int p = (id >> 8) & 7, tt = id & 255;
    int wvv = tt >> 6, lnn = tt & 63, qq = lnn >> 4, lmm = lnn & 15;
    int nt = p >> 1, s = p & 1;
    int n  = 64 * wvv + 16 * nt + lmm;
    int k0 = (id >> 11) * 64 + 32 * s + 4 * qq;
    v8s v;
    #pragma unroll
    for (int i = 0; i < 4; ++i) {
      v[i]     = (short)f2bf(W1[(size_t)(k0 + i) * D1 + n]);
      v[i + 4] = (short)f2bf(W1[(size_t)(k0 + 16 + i) * D1 + n]);
    }
    *(v8s*)(wimg + (size_t)id * 16) = v;
  }
  int id2 = id - 24576;
  if (id2 >= 0 && id2 < 4096) {  // W2: (kc 4, p 4, t 256)
    int p = (id2 >> 8) & 3, tt = id2 & 255;
    int wvv = tt >> 6, lnn = tt & 63, qq = lnn >> 4, lmm = lnn & 15;
    int nt = p >> 1, s = p & 1;
    int n  = 32 * wvv + 16 * nt + lmm;
    int k0 = (id2 >> 10) * 64 + 32 * s + 4 * qq;
    v8s v;
    #pragma unroll
    for (int i = 0; i < 4; ++i) {
      v[i]     = (short)f2bf(W2[(size_t)(k0 + i) * D2 + n]);
      v[i + 4] = (short)f2bf(W2[(size_t)(k0 + 16 + i) * D2 + n]);
    }
    *(v8s*)(wimg + W1_IMG_BYTES + (size_t)id2 * 16) = v;
  }
  int id3 = id - 28672;
  if (id3 >= 0 && id3 < 2048) {  // Ahat frags: (mt 4, s2 2, t 256), hi + lo
    int tt = id3 & 255, ms = id3 >> 8;
    int mt = ms >> 1, s2 = ms & 1;
    int lnn = tt & 63, qq = lnn >> 4, lmm = lnn & 15;
    int m = 16 * mt + lmm;
    v8s hi, lo;
    #pragma unroll
    for (int j = 0; j < 8; ++j) {
      int k = 32 * s2 + ((j & 4) << 2) + 4 * qq + (j & 3);
      float v = ahat(m, k);
      unsigned short h = f2bf(v);
      hi[j] = (short)h;
      lo[j] = (short)f2bf(v - bf2f(h));
    }
    *(v8s*)(wimg + AH_OFF + (size_t)id3 * 16) = hi;
    *(v8s*)(wimg + AH_OFF + 32768 + (size_t)id3 * 16) = lo;
  }
}

// ============================ main fused kernel ==============================
// 2 batches per block (R8 structure). LDS: sX0 [0,8K) sX1 [8K,16K) |
// sH1_0 [16K,48K) | sH1_1 [48K,80K). spool overlays dead sX. 80KB -> 2/CU.
#define SX0    0
#define SX1    8192
#define SH1_0  16384
#define SH1_1  49152
#define SPOOL0 0
#define SPOOL1 512
#define NSMEM7 81920

__device__ __forceinline__ void ldw8(v8s* dst, const char* base) {
  #pragma unroll
  for (int p = 0; p < 8; ++p) dst[p] = *(const v8s*)(base + p * 4096);
}
__device__ __forceinline__ void ldw4(v8s* dst, const char* base) {
  #pragma unroll
  for (int p = 0; p < 4; ++p) dst[p] = *(const v8s*)(base + p * 4096);
}
__device__ __forceinline__ void commit8(char* lds, const float4& a, const float4& b) {
  v8s v;
  v[0] = (short)f2bf(a.x); v[1] = (short)f2bf(a.y);
  v[2] = (short)f2bf(a.z); v[3] = (short)f2bf(a.w);
  v[4] = (short)f2bf(b.x); v[5] = (short)f2bf(b.y);
  v[6] = (short)f2bf(b.z); v[7] = (short)f2bf(b.w);
  *(v8s*)lds = v;
}

__global__ __launch_bounds__(256, 2) void gcn_fused10(
    const float* __restrict__ X, const char* __restrict__ wimg,
    const float* __restrict__ b1v, const float* __restrict__ b2v,
    const float* __restrict__ fcWv, const float* __restrict__ fcbv,
    float* __restrict__ out)
{
  __shared__ __align__(16) char smem[NSMEM7];
  const int t  = threadIdx.x;
  const int wv = t >> 6;
  const int ln = t & 63;
  const int q  = ln >> 4;
  const int lm = ln & 15;

  // zero pad rows 49-63 of both X buffers (once)
  if (t < 240) {
    int i = (t >= 120) ? t - 120 : t;
    int base = ((t >= 120) ? SX1 : SX0) + 6272 + i * 16;
    *(v4i*)(smem + base) = (v4i){0, 0, 0, 0};
  }

  // -------- X staging: 784 segments (2 batches x 49 rows x 8 frags) --------
  const float* X0 = X + (size_t)(2 * blockIdx.x) * (NN * D0);
  const float* X1 = X0 + NN * D0;

  const int g1 = t + 256;
  const int b1g = (g1 >= 392) ? 1 : 0;
  const bool act3 = (t < 16);
  const int s0 = t, s1 = g1 - 392 * b1g, s2 = t + 120, s3 = t + 376;
  const int r0 = s0 >> 3, f0 = s0 & 7;
  const int r1 = s1 >> 3, f1 = s1 & 7;
  const int r2 = s2 >> 3, f2 = s2 & 7;
  const int r3 = s3 >> 3, f3 = s3 & 7;
  const float* base0 = X0 + r0 * D0 + 32 * (f0 >> 2) + 4 * (f0 & 3);
  const float* base1 = (b1g ? X1 : X0) + r1 * D0 + 32 * (f1 >> 2) + 4 * (f1 & 3);
  const float* base2 = X1 + r2 * D0 + 32 * (f2 >> 2) + 4 * (f2 & 3);
  const float* base3_ = X1 + r3 * D0 + 32 * (f3 >> 2) + 4 * (f3 & 3);
  const float* base3 = act3 ? base3_ : base0;     // dummy in-bounds when idle
  const int lds0 = SX0 + ((r0 * 128 + 16 * f0) ^ ((r0 & 7) << 4));
  const int lds1 = (b1g ? SX1 : SX0) + ((r1 * 128 + 16 * f1) ^ ((r1 & 7) << 4));
  const int lds2 = SX1 + ((r2 * 128 + 16 * f2) ^ ((r2 & 7) << 4));
  const int lds3 = SX1 + (((r3 & 63) * 128 + 16 * f3) ^ ((r3 & 7) << 4));

  const int tofs = t * 16;

  v4f accA[4][4], accB[4][4];
  #pragma unroll
  for (int i = 0; i < 4; ++i)
    #pragma unroll
    for (int j = 0; j < 4; ++j) {
      accA[i][j] = (v4f){0.f, 0.f, 0.f, 0.f};
      accB[i][j] = (v4f){0.f, 0.f, 0.f, 0.f};
    }

  // prologue: W chunk0 + X chunk0 in flight
  v8s wA[8];
  ldw8(wA, wimg + tofs);
  float4 p0a = *(const float4*)(base0);
  float4 p0b = *(const float4*)(base0 + 16);
  float4 p1a = *(const float4*)(base1);
  float4 p1b = *(const float4*)(base1 + 16);
  float4 p2a = *(const float4*)(base2);
  float4 p2b = *(const float4*)(base2 + 16);
  float4 p3a = *(const float4*)(base3);
  float4 p3b = *(const float4*)(base3 + 16);

  for (int kc = 0; kc < 12; ++kc) {
    // barrier A: previous MFMA readers of sX are done
    __builtin_amdgcn_sched_barrier(0);
    __builtin_amdgcn_s_barrier();
    __builtin_amdgcn_sched_barrier(0);
    // commit chunk kc
    commit8((char*)smem + lds0, p0a, p0b);
    commit8((char*)smem + lds1, p1a, p1b);
    commit8((char*)smem + lds2, p2a, p2b);
    if (act3) commit8((char*)smem + lds3, p3a, p3b);
    // issue X chunk kc+1
    if (kc < 11) {
      const int o = (kc + 1) * 64;
      p0a = *(const float4*)(base0 + o);
      p0b = *(const float4*)(base0 + o + 16);
      p1a = *(const float4*)(base1 + o);
      p1b = *(const float4*)(base1 + o + 16);
      p2a = *(const float4*)(base2 + o);
      p2b = *(const float4*)(base2 + o + 16);
      p3a = *(const float4*)(base3 + o);
      p3b = *(const float4*)(base3 + o + 16);
    }
    __builtin_amdgcn_sched_barrier(0);
    asm volatile("s_waitcnt lgkmcnt(0)" ::: "memory");
    __builtin_amdgcn_s_barrier();
    __builtin_amdgcn_sched_barrier(0);
    // MFMA: batch0 (sX0) then batch1 (sX1), shared wA
    #pragma unroll
    for (int ks = 0; ks < 2; ++ks) {
      const int off = ks * 64 + (q << 4);
      v8s af[4];
      #pragma unroll
      for (int mt = 0; mt < 4; ++mt) {
        int row = mt * 16 + lm;
        af[mt] = *(const v8s*)(smem + SX0 + ((row * 128 + off) ^ ((row & 7) << 4)));
      }
      #pragma unroll
      for (int mt = 0; mt < 4; ++mt)
        #pragma unroll
        for (int nt = 0; nt < 4; ++nt)
          accA[mt][nt] = __builtin_amdgcn_mfma_f32_16x16x32_bf16(af[mt], wA[2 * nt + ks], accA[mt][nt], 0, 0, 0);
    }
    #pragma unroll
    for (int ks = 0; ks < 2; ++ks) {
      const int off = ks * 64 + (q << 4);
      v8s af[4];
      #pragma unroll
      for (int mt = 0; mt < 4; ++mt) {
        int row = mt * 16 + lm;
        af[mt] = *(const v8s*)(smem + SX1 + ((row * 128 + off) ^ ((row & 7) << 4)));
      }
      #pragma unroll
      for (int mt = 0; mt < 4; ++mt)
        #pragma unroll
        for (int nt = 0; nt < 4; ++nt)
          accB[mt][nt] = __builtin_amdgcn_mfma_f32_16x16x32_bf16(af[mt], wA[2 * nt + ks], accB[mt][nt], 0, 0, 0);
    }
    // reload W for next chunk (after last use; latency hidden by next stage)
    if (kc < 11) ldw8(wA, wimg + (kc + 1) * 32768 + tofs);
  }

  // issue Ahat fragment loads (latency hides under the pack below)
  const char* ahimg = wimg + AH_OFF;
  v8s afH[4][2], afL[4][2];
  #pragma unroll
  for (int mt = 0; mt < 4; ++mt)
    #pragma unroll
    for (int s2 = 0; s2 < 2; ++s2) {
      const int idx = ((mt * 2 + s2) * 256 + t) * 16;
      afH[mt][s2] = *(const v8s*)(ahimg + idx);
      afL[mt][s2] = *(const v8s*)(ahimg + 32768 + idx);
    }

  // -------- pack C1 accumulators to bf16 b-frags (halves reg footprint) --------
  v8s bA[2][4], bB[2][4];
  #pragma unroll
  for (int s2 = 0; s2 < 2; ++s2)
    #pragma unroll
    for (int nt = 0; nt < 4; ++nt) {
      v8s a, b;
      #pragma unroll
      for (int i = 0; i < 4; ++i) {
        a[i]     = (short)f2bf(accA[2 * s2][nt][i]);
        a[i + 4] = (short)f2bf(accA[2 * s2 + 1][nt][i]);
        b[i]     = (short)f2bf(accB[2 * s2][nt][i]);
        b[i + 4] = (short)f2bf(accB[2 * s2 + 1][nt][i]);
      }
      bA[s2][nt] = a; bB[s2][nt] = b;
    }

  float bi[4];
  #pragma unroll
  for (int nt = 0; nt < 4; ++nt) bi[nt] = b1v[64 * wv + 16 * nt + lm];

  // ====== AGG1 per batch: H1 = relu(Ahat @ C1 + b1) -> sH1_b ======
  #pragma unroll
  for (int bb = 0; bb < 2; ++bb) {
    v4f ag[4][4];
    #pragma unroll
    for (int mt = 0; mt < 4; ++mt)
      #pragma unroll
      for (int nt = 0; nt < 4; ++nt)
        ag[mt][nt] = (v4f){bi[nt], bi[nt], bi[nt], bi[nt]};
    #pragma unroll
    for (int s2 = 0; s2 < 2; ++s2)
      #pragma unroll
      for (int nt = 0; nt < 4; ++nt) {
        v8s b = (bb == 0) ? bA[s2][nt] : bB[s2][nt];
        #pragma unroll
        for (int mt = 0; mt < 4; ++mt) {
          ag[mt][nt] = __builtin_amdgcn_mfma_f32_16x16x32_bf16(afL[mt][s2], b, ag[mt][nt], 0, 0, 0);
          ag[mt][nt] = __builtin_amdgcn_mfma_f32_16x16x32_bf16(afH[mt][s2], b, ag[mt][nt], 0, 0, 0);
        }
      }
    const int hbase = (bb == 0) ? SH1_0 : SH1_1;
    #pragma unroll
    for (int mt = 0; mt < 4; ++mt)
      #pragma unroll
      for (int nt = 0; nt < 4; ++nt) {
        int ch  = 64 * wv + 16 * nt + lm;
        int chb = 2 * permk(ch);
        #pragma unroll
        for (int r = 0; r < 4; ++r) {
          int row = 16 * mt + 4 * q + r;
          float hv = fmaxf(ag[mt][nt][r], 0.f);
          int byte = (row * 512 + chb) ^ ((row & 7) << 4);
          *(unsigned short*)(smem + hbase + byte) = f2bf(hv);
        }
      }
  }

  // issue W2 loads now (L2 latency hides under the barrier)
  const char* w2img = wimg + W1_IMG_BYTES;
  v8s w2c0[4], w2c1[4], w2c2[4], w2c3[4];
  ldw4(w2c0, w2img + tofs);
  ldw4(w2c1, w2img + 16384 + tofs);
  ldw4(w2c2, w2img + 2 * 16384 + tofs);
  ldw4(w2c3, w2img + 3 * 16384 + tofs);

  __builtin_amdgcn_sched_barrier(0);
  asm volatile("s_waitcnt lgkmcnt(0)" ::: "memory");
  __builtin_amdgcn_s_barrier();
  __builtin_amdgcn_sched_barrier(0);

  // ====== GEMM2 + AGG2 + pool per batch (w2c shared, no barriers) ======
  float b2i0 = b2v[32 * wv + lm];
  float b2i1 = b2v[32 * wv + 16 + lm];

  #pragma unroll
  for (int bb = 0; bb < 2; ++bb) {
    const int hbase = (bb == 0) ? SH1_0 : SH1_1;
    v4f acc3[4][2];
    #pragma unroll
    for (int i = 0; i < 4; ++i) {
      acc3[i][0] = (v4f){0.f, 0.f, 0.f, 0.f};
      acc3[i][1] = (v4f){0.f, 0.f, 0.f, 0.f};
    }
    #pragma unroll
    for (int kc = 0; kc < 4; ++kc)
      #pragma unroll
      for (int ks = 0; ks < 2; ++ks) {
        const int off = ks * 64 + (q << 4);
        v8s af[4];
        #pragma unroll
        for (int mt = 0; mt < 4; ++mt) {
          int row = mt * 16 + lm;
          int byte = (row * 512 + kc * 128 + off) ^ ((row & 7) << 4);
          af[mt] = *(const v8s*)(smem + hbase + byte);
        }
        const v8s* wc = (kc == 0) ? w2c0 : (kc == 1) ? w2c1 : (kc == 2) ? w2c2 : w2c3;
        #pragma unroll
        for (int mt = 0; mt < 4; ++mt)
          #pragma unroll
          for (int nt = 0; nt < 2; ++nt)
            acc3[mt][nt] = __builtin_amdgcn_mfma_f32_16x16x32_bf16(af[mt], wc[2 * nt + ks], acc3[mt][nt], 0, 0, 0);
      }
    // AGG2
    v4f a2[4][2];
    #pragma unroll
    for (int mt = 0; mt < 4; ++mt) {
      a2[mt][0] = (v4f){b2i0, b2i0, b2i0, b2i0};
      a2[mt][1] = (v4f){b2i1, b2i1, b2i1, b2i1};
    }
    #pragma unroll
    for (int s2 = 0; s2 < 2; ++s2)
      #pragma unroll
      for (int nt = 0; nt < 2; ++nt) {
        v8s b;
        #pragma unroll
        for (int i = 0; i < 4; ++i) {
          b[i]     = (short)f2bf(acc3[2 * s2][nt][i]);
          b[i + 4] = (short)f2bf(acc3[2 * s2 + 1][nt][i]);
        }
        #pragma unroll
        for (int mt = 0; mt < 4; ++mt) {
          a2[mt][nt] = __builtin_amdgcn_mfma_f32_16x16x32_bf16(afL[mt][s2], b, a2[mt][nt], 0, 0, 0);
          a2[mt][nt] = __builtin_amdgcn_mfma_f32_16x16x32_bf16(afH[mt][s2], b, a2[mt][nt], 0, 0, 0);
        }
      }
    // pool: rows 0..47 (mt<3) + row 48 (q==0, r==0)
    float ps0 = 0.f, ps1 = 0.f;
    #pragma unroll
    for (int mt = 0; mt < 3; ++mt)
      #pragma unroll
      for (int r = 0; r < 4; ++r) {
        ps0 += fmaxf(a2[mt][0][r], 0.f);
        ps1 += fmaxf(a2[mt][1][r], 0.f);
      }
    if (q == 0) {
      ps0 += fmaxf(a2[3][0][0], 0.f);
      ps1 += fmaxf(a2[3][1][0], 0.f);
    }
    ps0 += __shfl_xor(ps0, 16); ps0 += __shfl_xor(ps0, 32);
    ps1 += __shfl_xor(ps1, 16); ps1 += __shfl_xor(ps1, 32);
    float* spool = (float*)(smem + ((bb == 0) ? SPOOL0 : SPOOL1));
    if (q == 0) {
      spool[32 * wv + lm]      = ps0 * (1.0f / 49.0f);
      spool[32 * wv + 16 + lm] = ps1 * (1.0f / 49.0f);
    }
  }
  __syncthreads();
  // fc: wave w handles batch (w>>1), channels {2*(w&1), 2*(w&1)+1}; lane-parallel over d
  {
    const int bb = wv >> 1;
    const int c0 = (wv & 1) * 2;
    const float* spool = (const float*)(smem + (bb ? SPOOL1 : SPOOL0));
    float d0 = spool[ln];
    float d1 = spool[ln + 64];
    float a0 = d0 * fcWv[ln * 4 + c0]     + d1 * fcWv[(ln + 64) * 4 + c0];
    float a1 = d0 * fcWv[ln * 4 + c0 + 1] + d1 * fcWv[(ln + 64) * 4 + c0 + 1];
    #pragma unroll
    for (int s = 32; s; s >>= 1) { a0 += __shfl_xor(a0, s); a1 += __shfl_xor(a1, s); }
    if (ln == 0) {
      out[(size_t)(2 * blockIdx.x + bb) * 4 + c0]     = a0 + fcbv[c0];
      out[(size_t)(2 * blockIdx.x + bb) * 4 + c0 + 1] = a1 + fcbv[c0 + 1];
    }
  }
}

// ===================== fallback (round-1 kernel, no d_ws) =====================
#define OFF_SX    0
#define OFF_SWT   8192
#define OFF_SC    0
#define OFF_SWT2  0
#define OFF_SPOOL 25872
#define OFF_SPF   30096
#define OFF_SH1   40960
#define OFF_NBRW  73728
#define OFF_NBRI  75492
#define OFF_B1    77256
#define OFF_B2    78280
#define OFF_FCW   78792
#define OFF_FCB   80840
#define SMEM_SZ   80856

__global__ __launch_bounds__(256, 2) void gcn_fused_fb(
    const float* __restrict__ X, const float* __restrict__ W1,
    const float* __restrict__ b1v, const float* __restrict__ W2,
    const float* __restrict__ b2v, const float* __restrict__ fcWv,
    const float* __restrict__ fcbv, float* __restrict__ out)
{
  __shared__ __align__(16) char smem[SMEM_SZ];
  const int t  = threadIdx.x;
  const int wv = t >> 6;
  const int ln = t & 63;
  const int q  = ln >> 4;
  const int lm = ln & 15;

  float* nbrW = (float*)(smem + OFF_NBRW);
  int*   nbrI = (int*)  (smem + OFF_NBRI);
  float* b1s  = (float*)(smem + OFF_B1);
  float* b2s  = (float*)(smem + OFF_B2);
  float* fcWs = (float*)(smem + OFF_FCW);
  float* fcbs = (float*)(smem + OFF_FCB);
  float* sC   = (float*)(smem + OFF_SC);

  if (t < D1) b1s[t] = b1v[t];
  if (t < D2) b2s[t] = b2v[t];
  fcWs[t]       = fcWv[t];
  fcWs[t + 256] = fcWv[t + 256];
  if (t < 4) fcbs[t] = fcbv[t];
  if (t < NN) {
    int y = t / 7, x = t % 7;
    float rm = rsqrtf((float)((1 + (y > 0) + (y < 6)) * (1 + (x > 0) + (x < 6))) + 1.0f);
    int cnt = 0;
    for (int dy = -1; dy <= 1; ++dy)
      for (int dx = -1; dx <= 1; ++dx) {
        int ny = y + dy, nx = x + dx;
        if (ny >= 0 && ny < 7 && nx >= 0 && nx < 7) {
          int n = ny * 7 + nx;
          float rn = rsqrtf((float)((1 + (ny > 0) + (ny < 6)) * (1 + (nx > 0) + (nx < 6))) + 1.0f);
          nbrW[t * 9 + cnt] = ((n == t) ? 2.0f : 1.0f) * rm * rn;
          nbrI[t * 9 + cnt] = n;
          ++cnt;
        }
      }
    for (; cnt < 9; ++cnt) { nbrW[t * 9 + cnt] = 0.0f; nbrI[t * 9 + cnt] = 0; }
  }
  __syncthreads();

  const float* Xb = X + (size_t)blockIdx.x * (NN * D0);
  v4f acc[4][4];
  #pragma unroll
  for (int i = 0; i < 4; ++i)
    #pragma unroll
    for (int j = 0; j < 4; ++j)
      acc[i][j] = (v4f){0.f, 0.f, 0.f, 0.f};

  for (int kc = 0; kc < 12; ++kc) {
    __syncthreads();
    #pragma unroll
    for (int p = 0; p < 4; ++p) {
      int idx = t + 256 * p;
      int row = idx >> 4;
      int k4  = (idx & 15) << 2;
      float4 v = {0.f, 0.f, 0.f, 0.f};
      if (row < NN) v = *(const float4*)(Xb + row * D0 + kc * 64 + k4);
      ushort4 s;
      s.x = f2bf(v.x); s.y = f2bf(v.y); s.z = f2bf(v.z); s.w = f2bf(v.w);
      int byte = row * 128 + 2 * permk(k4);
      byte ^= (row & 7) << 4;
      *(ushort4*)(smem + OFF_SX + byte) = s;
    }
    #pragma unroll
    for (int p = 0; p < 4; ++p) {
      int bid2 = t + 256 * p;
      int k0 = (bid2 & 15) << 2;
      int n0 = (bid2 >> 4) << 2;
      const float* wp = W1 + (size_t)(kc * 64 + k0) * D1 + n0;
      float4 r0 = *(const float4*)(wp);
      float4 r1 = *(const float4*)(wp + D1);
      float4 r2 = *(const float4*)(wp + 2 * D1);
      float4 r3 = *(const float4*)(wp + 3 * D1);
      int kb = 2 * permk(k0);
      ushort4 s; int byte;
      s.x = f2bf(r0.x); s.y = f2bf(r1.x); s.z = f2bf(r2.x); s.w = f2bf(r3.x);
      byte = (n0 + 0) * 128 + kb; byte ^= ((n0 + 0) & 7) << 4;
      *(ushort4*)(smem + OFF_SWT + byte) = s;
      s.x = f2bf(r0.y); s.y = f2bf(r1.y); s.z = f2bf(r2.y); s.w = f2bf(r3.y);
      byte = (n0 + 1) * 128 + kb; byte ^= ((n0 + 1) & 7) << 4;
      *(ushort4*)(smem + OFF_SWT + byte) = s;
      s.x = f2bf(r0.z); s.y = f2bf(r1.z); s.z = f2bf(r2.z); s.w = f2bf(r3.z);
      byte = (n0 + 2) * 128 + kb; byte ^= ((n0 + 2) & 7) << 4;
      *(ushort4*)(smem + OFF_SWT + byte) = s;
      s.x = f2bf(r0.w); s.y = f2bf(r1.w); s.z = f2bf(r2.w); s.w = f2bf(r3.w);
      byte = (n0 + 3) * 128 + kb; byte ^= ((n0 + 3) & 7) << 4;
      *(ushort4*)(smem + OFF_SWT + byte) = s;
    }
    __syncthreads();
    #pragma unroll
    for (int ks = 0; ks < 2; ++ks) {
      int off = ks * 64 + (q << 4);
      v8s af[4], bf[4];
      #pragma unroll
      for (int mt = 0; mt < 4; ++mt) {
        int row = mt * 16 + lm;
        int byte = row * 128 + off; byte ^= (row & 7) << 4;
        af[mt] = *(const v8s*)(smem + OFF_SX + byte);
      }
      #pragma unroll
      for (int nt = 0; nt < 4; ++nt) {
        int n = (wv * 4 + nt) * 16 + lm;
        int byte = n * 128 + off; byte ^= (n & 7) << 4;
        bf[nt] = *(const v8s*)(smem + OFF_SWT + byte);
      }
      #pragma unroll
      for (int mt = 0; mt < 4; ++mt)
        #pragma unroll
        for (int nt = 0; nt < 4; ++nt)
          acc[mt][nt] = __builtin_amdgcn_mfma_f32_16x16x32_bf16(af[mt], bf[nt], acc[mt][nt], 0, 0, 0);
    }
  }

  #pragma unroll
  for (int h = 0; h < 2; ++h) {
    __syncthreads();
    if ((wv >> 1) == h) {
      #pragma unroll
      for (int mt = 0; mt < 4; ++mt) {
        int rbase = mt * 16 + (q << 2);
        #pragma unroll
        for (int nt = 0; nt < 4; ++nt) {
          int c = ((wv & 1) * 4 + nt) * 16 + lm;
          #pragma unroll
          for (int r = 0; r < 4; ++r) {
            int row = rbase + r;
            if (row < NN) sC[row * 132 + c] = acc[mt][nt][r];
          }
        }
      }
    }
    __syncthreads();
    for (int p = 0; p < 7; ++p) {
      int idx = t + 256 * p;
      if (idx < NN * 32) {
        int m  = idx >> 5;
        int d4 = (idx & 31) << 2;
        int dg = h * 128 + d4;
        float a0 = b1s[dg], a1 = b1s[dg + 1], a2 = b1s[dg + 2], a3 = b1s[dg + 3];
        #pragma unroll
        for (int e = 0; e < 9; ++e) {
          float w = nbrW[m * 9 + e];
          int   n = nbrI[m * 9 + e];
          float4 cv = *(const float4*)(sC + n * 132 + d4);
          a0 += w * cv.x; a1 += w * cv.y; a2 += w * cv.z; a3 += w * cv.w;
        }
        a0 = fmaxf(a0, 0.f); a1 = fmaxf(a1, 0.f); a2 = fmaxf(a2, 0.f); a3 = fmaxf(a3, 0.f);
        ushort4 s; s.x = f2bf(a0); s.y = f2bf(a1); s.z = f2bf(a2); s.w = f2bf(a3);
        int byte = m * 512 + 2 * permk(dg);
        byte ^= (m & 7) << 4;
        *(ushort4*)(smem + OFF_SH1 + byte) = s;
      }
    }
  }

  v4f acc2[4][2];
  #pragma unroll
  for (int i = 0; i < 4; ++i) { acc2[i][0] = (v4f){0.f,0.f,0.f,0.f}; acc2[i][1] = (v4f){0.f,0.f,0.f,0.f}; }

  for (int kc = 0; kc < 4; ++kc) {
    __syncthreads();
    #pragma unroll
    for (int p = 0; p < 2; ++p) {
      int bid2 = t + 256 * p;
      int k0 = (bid2 & 15) << 2;
      int n0 = (bid2 >> 4) << 2;
      const float* wp = W2 + (size_t)(kc * 64 + k0) * D2 + n0;
      float4 r0 = *(const float4*)(wp);
      float4 r1 = *(const float4*)(wp + D2);
      float4 r2 = *(const float4*)(wp + 2 * D2);
      float4 r3 = *(const float4*)(wp + 3 * D2);
      int kb = 2 * permk(k0);
      ushort4 s; int byte;
      s.x = f2bf(r0.x); s.y = f2bf(r1.x); s.z = f2bf(r2.x); s.w = f2bf(r3.x);
      byte = (n0 + 0) * 128 + kb; byte ^= ((n0 + 0) & 7) << 4;
      *(ushort4*)(smem + OFF_SWT2 + byte) = s;
      s.x = f2bf(r0.y); s.y = f2bf(r1.y); s.z = f2bf(r2.y); s.w = f2bf(r3.y);
      byte = (n0 + 1) * 128 + kb; byte ^= ((n0 + 1) & 7) << 4;
      *(ushort4*)(smem + OFF_SWT2 + byte) = s;
      s.x = f2bf(r0.z); s.y = f2bf(r1.z); s.z = f2bf(r2.z); s.w = f2bf(r3.z);
      byte = (n0 + 2) * 128 + kb; byte ^= ((n0 + 2) & 7) << 4;
      *(ushort4*)(smem + OFF_SWT2 + byte) = s;
      s.x = f2bf(r0.w); s.y = f2bf(r1.w); s.z = f2bf(r2.w); s.w = f2bf(r3.w);
      byte = (n0 + 3) * 128 + kb; byte ^= ((n0 + 3) & 7) << 4;
      *(ushort4*)(smem + OFF_SWT2 + byte) = s;
    }
    __syncthreads();
    #pragma unroll
    for (int ks = 0; ks < 2; ++ks) {
      int off = ks * 64 + (q << 4);
      v8s af[4], bf2[2];
      #pragma unroll
      for (int mt = 0; mt < 4; ++mt) {
        int row = mt * 16 + lm;
        int byte = row * 512 + kc * 128 + off; byte ^= (row & 7) << 4;
        af[mt] = *(const v8s*)(smem + OFF_SH1 + byte);
      }
      #pragma unroll
      for (int nt = 0; nt < 2; ++nt) {
        int n = (wv * 2 + nt) * 16 + lm;
        int byte = n * 128 + off; byte ^= (n & 7) << 4;
        bf2[nt] = *(const v8s*)(smem + OFF_SWT2 + byte);
      }
      #pragma unroll
      for (int mt = 0; mt < 4; ++mt)
        #pragma unroll
        for (int nt = 0; nt < 2; ++nt)
          acc2[mt][nt] = __builtin_amdgcn_mfma_f32_16x16x32_bf16(af[mt], bf2[nt], acc2[mt][nt], 0, 0, 0);
    }
  }

  __syncthreads();
  #pragma unroll
  for (int mt = 0; mt < 4; ++mt) {
    int rbase = mt * 16 + (q << 2);
    #pragma unroll
    for (int nt = 0; nt < 2; ++nt) {
      int c = (wv * 2 + nt) * 16 + lm;
      #pragma unroll
      for (int r = 0; r < 4; ++r) {
        int row = rbase + r;
        if (row < NN) sC[row * 132 + c] = acc2[mt][nt][r];
      }
    }
  }
  __syncthreads();
  {
    int d4 = (t & 31) << 2;
    int g  = t >> 5;
    float p0 = 0.f, p1 = 0.f, p2 = 0.f, p3 = 0.f;
    int m0 = g * 7, m1 = (g * 7 + 7 < NN) ? (g * 7 + 7) : NN;
    for (int m = m0; m < m1; ++m) {
      float a0 = b2s[d4], a1 = b2s[d4 + 1], a2 = b2s[d4 + 2], a3 = b2s[d4 + 3];
      #pragma unroll
      for (int e = 0; e < 9; ++e) {
        float w = nbrW[m * 9 + e];
        int   n = nbrI[m * 9 + e];
        float4 cv = *(const float4*)(sC + n * 132 + d4);
        a0 += w * cv.x; a1 += w * cv.y; a2 += w * cv.z; a3 += w * cv.w;
      }
      p0 += fmaxf(a0, 0.f); p1 += fmaxf(a1, 0.f); p2 += fmaxf(a2, 0.f); p3 += fmaxf(a3, 0.f);
    }
    float* sp = (float*)(smem + OFF_SPOOL) + g * 132 + d4;
    sp[0] = p0; sp[1] = p1; sp[2] = p2; sp[3] = p3;
  }
  __syncthreads();
  if (t < D2) {
    const float* sp = (const float*)(smem + OFF_SPOOL);
    float s = 0.f;
    #pragma unroll
    for (int g = 0; g < 8; ++g) s += sp[g * 132 + t];
    ((float*)(smem + OFF_SPF))[t] = s * (1.0f / 49.0f);
  }
  __syncthreads();
  if (t < 4) {
    const float* pf = (const float*)(smem + OFF_SPF);
    float a = fcbs[t];
    for (int d = 0; d < D2; ++d) a += pf[d] * fcWs[d * 4 + t];
    out[(size_t)blockIdx.x * 4 + t] = a;
  }
}

extern "C" void kernel_launch(void* const* d_in, const int* in_sizes, int n_in,
                              void* d_out, int out_size, void* d_ws, size_t ws_size,
                              hipStream_t stream) {
  const float* X   = (const float*)d_in[0];
  const float* W1  = (const float*)d_in[1];
  const float* b1  = (const float*)d_in[2];
  const float* W2  = (const float*)d_in[3];
  const float* b2  = (const float*)d_in[4];
  const float* fcW = (const float*)d_in[5];
  const float* fcb = (const float*)d_in[6];
  float* out = (float*)d_out;
  int B = in_sizes[0] / (NN * D0);   // 4096
  if (d_ws != nullptr && ws_size >= (size_t)WS_NEEDED && (B % 2) == 0) {
    prep_w<<<120, 256, 0, stream>>>(W1, W2, (char*)d_ws);
    gcn_fused10<<<B / 2, 256, 0, stream>>>(X, (const char*)d_ws, b1, b2, fcW, fcb, out);
  } else {
    gcn_fused_fb<<<B, 256, 0, stream>>>(X, W1, b1, W2, b2, fcW, fcb, out);
  }
}

// Round 11
// 180.142 us; speedup vs baseline: 1.1278x; 1.0155x over previous
//
#include <hip/hip_runtime.h>

#define NN 49
#define D0 768
#define D1 256
#define D2 128

typedef short v8s __attribute__((ext_vector_type(8)));
typedef float v4f __attribute__((ext_vector_type(4)));
typedef int   v4i __attribute__((ext_vector_type(4)));

__device__ __forceinline__ unsigned short f2bf(float f) {
  unsigned int u = __float_as_uint(f);
  u += 0x7FFFu + ((u >> 16) & 1u);   // RNE; inputs finite
  return (unsigned short)(u >> 16);
}
__device__ __forceinline__ float bf2f(unsigned short u) {
  return __uint_as_float((unsigned)u << 16);
}

// bijective within each 32-wide k-block: packs lane-group q's 8 frag elems
// (k = 32s + 4q+i and 32s + 16 + 4q+i) into contiguous bytes [64s+16q, +16)
__device__ __forceinline__ int permk(int k) {
  return (k & ~31) | ((k & 12) << 1) | ((k & 16) >> 2) | (k & 3);
}

// GCN-normalized 7x7-grid adjacency entry (exact-zero outside stencil / pad)
__device__ __forceinline__ float ahat(int m, int k) {
  if (m >= NN || k >= NN) return 0.f;
  int ym = m / 7, xm = m % 7, yk = k / 7, xk = k % 7;
  int dy = ym - yk, dx = xm - xk;
  if (dy < -1 || dy > 1 || dx < -1 || dx > 1) return 0.f;
  float rm = rsqrtf((float)((1 + (ym > 0) + (ym < 6)) * (1 + (xm > 0) + (xm < 6))) + 1.0f);
  float rk = rsqrtf((float)((1 + (yk > 0) + (yk < 6)) * (1 + (xk > 0) + (xk < 6))) + 1.0f);
  return ((m == k) ? 2.0f : 1.0f) * rm * rk;
}

// ======================= setup: pre-convert weights ==========================
// Per-THREAD fragment images:
// W1: byte = (kc*2048 + p*256 + t)*16, p = 2*nt + s.  W2: p = 2*nt + s (nt<2).
// AH: Ahat hi/lo fragments, entry ((mt*2+s2)*256 + t)*16; hi then lo (32KB each).
#define W1_IMG_BYTES 393216
#define AH_OFF       458752
#define WS_NEEDED    524288

__global__ void prep_w(const float* __restrict__ W1, const float* __restrict__ W2,
                       char* __restrict__ wimg) {
  int id = blockIdx.x * 256 + threadIdx.x;
  if (id < 24576) {              // W1: (kc 12, p 8, t 256)
    int p = (id >> 8) & 7, tt = id & 255;
    int wvv = tt >> 6, lnn = tt & 63, qq = lnn >> 4, lmm = lnn & 15;
    int nt = p >> 1, s = p & 1;
    int n  = 64 * wvv + 16 * nt + lmm;
    int k0 = (id >> 11) * 64 + 32 * s + 4 * qq;
    v8s v;
    #pragma unroll
    for (int i = 0; i < 4; ++i) {
      v[i]     = (short)f2bf(W1[(size_t)(k0 + i) * D1 + n]);
      v[i + 4] = (short)f2bf(W1[(size_t)(k0 + 16 + i) * D1 + n]);
    }
    *(v8s*)(wimg + (size_t)id * 16) = v;
  }
  int id2 = id - 24576;
  if (id2 >= 0 && id2 < 4096) {  // W2: (kc 4, p 4, t 256)
    int p = (id2 >> 8) & 3, tt = id2 & 255;
    int wvv = tt >> 6, lnn = tt & 63, qq = lnn >> 4, lmm = lnn & 15;
    int nt = p >> 1, s = p & 1;
    int n  = 32 * wvv + 16 * nt + lmm;
    int k0 = (id2 >> 10) * 64 + 32 * s + 4 * qq;
    v8s v;
    #pragma unroll
    for (int i = 0; i < 4; ++i) {
      v[i]     = (short)f2bf(W2[(size_t)(k0 + i) * D2 + n]);
      v[i + 4] = (short)f2bf(W2[(size_t)(k0 + 16 + i) * D2 + n]);
    }
    *(v8s*)(wimg + W1_IMG_BYTES + (size_t)id2 * 16) = v;
  }
  int id3 = id - 28672;
  if (id3 >= 0 && id3 < 2048) {  // Ahat frags: (mt 4, s2 2, t 256), hi + lo
    int tt = id3 & 255, ms = id3 >> 8;
    int mt = ms >> 1, s2 = ms & 1;
    int lnn = tt & 63, qq = lnn >> 4, lmm = lnn & 15;
    int m = 16 * mt + lmm;
    v8s hi, lo;
    #pragma unroll
    for (int j = 0; j < 8; ++j) {
      int k = 32 * s2 + ((j & 4) << 2) + 4 * qq + (j & 3);
      float v = ahat(m, k);
      unsigned short h = f2bf(v);
      hi[j] = (short)h;
      lo[j] = (short)f2bf(v - bf2f(h));
    }
    *(v8s*)(wimg + AH_OFF + (size_t)id3 * 16) = hi;
    *(v8s*)(wimg + AH_OFF + 32768 + (size_t)id3 * 16) = lo;
  }
}

// ============================ main fused kernel ==============================
// 2 batches per block, chunk-parity double-buffered sX, ONE barrier per chunk.
// LDS: sX[parity][batch] = parity*16384 + batch*8192, [0,32K)  (K-loop only)
//      sH1_0 [0,32K)  sH1_1 [32K,64K)   (overlay sX after K-loop barrier)
//      spool0 @64K, spool1 @64K+512.  Total 66048 -> 2 blocks/CU.
#define SXP    16384   // parity stride
#define SXB    8192    // batch stride
#define SH1_0  0
#define SH1_1  32768
#define SPOOL0 65536
#define SPOOL1 66048
#define NSMEM11 66560

__device__ __forceinline__ void ldw8(v8s* dst, const char* base) {
  #pragma unroll
  for (int p = 0; p < 8; ++p) dst[p] = *(const v8s*)(base + p * 4096);
}
__device__ __forceinline__ void ldw4(v8s* dst, const char* base) {
  #pragma unroll
  for (int p = 0; p < 4; ++p) dst[p] = *(const v8s*)(base + p * 4096);
}
__device__ __forceinline__ void commit8(char* lds, const float4& a, const float4& b) {
  v8s v;
  v[0] = (short)f2bf(a.x); v[1] = (short)f2bf(a.y);
  v[2] = (short)f2bf(a.z); v[3] = (short)f2bf(a.w);
  v[4] = (short)f2bf(b.x); v[5] = (short)f2bf(b.y);
  v[6] = (short)f2bf(b.z); v[7] = (short)f2bf(b.w);
  *(v8s*)lds = v;
}

__global__ __launch_bounds__(256, 2) void gcn_fused11(
    const float* __restrict__ X, const char* __restrict__ wimg,
    const float* __restrict__ b1v, const float* __restrict__ b2v,
    const float* __restrict__ fcWv, const float* __restrict__ fcbv,
    float* __restrict__ out)
{
  __shared__ __align__(16) char smem[NSMEM11];
  const int t  = threadIdx.x;
  const int wv = t >> 6;
  const int ln = t & 63;
  const int q  = ln >> 4;
  const int lm = ln & 15;

  // zero pad rows 49-63 of all 4 sX buffers (once)
  if (t < 120) {
    #pragma unroll
    for (int b = 0; b < 4; ++b)
      *(v4i*)(smem + b * 8192 + 6272 + t * 16) = (v4i){0, 0, 0, 0};
  }

  // -------- X staging: 784 segments (2 batches x 49 rows x 8 frags) --------
  const float* X0 = X + (size_t)(2 * blockIdx.x) * (NN * D0);
  const float* X1 = X0 + NN * D0;

  const int g1 = t + 256;
  const int b1g = (g1 >= 392) ? 1 : 0;
  const bool act3 = (t < 16);
  const int s0 = t, s1 = g1 - 392 * b1g, s2 = t + 120, s3 = t + 376;
  const int r0 = s0 >> 3, f0 = s0 & 7;
  const int r1 = s1 >> 3, f1 = s1 & 7;
  const int r2 = s2 >> 3, f2 = s2 & 7;
  const int r3 = s3 >> 3, f3 = s3 & 7;
  const float* base0 = X0 + r0 * D0 + 32 * (f0 >> 2) + 4 * (f0 & 3);
  const float* base1 = (b1g ? X1 : X0) + r1 * D0 + 32 * (f1 >> 2) + 4 * (f1 & 3);
  const float* base2 = X1 + r2 * D0 + 32 * (f2 >> 2) + 4 * (f2 & 3);
  const float* base3_ = X1 + r3 * D0 + 32 * (f3 >> 2) + 4 * (f3 & 3);
  const float* base3 = act3 ? base3_ : base0;     // dummy in-bounds when idle
  // batch-relative LDS offsets (add parity*SXP at commit)
  const int lds0 = ((r0 * 128 + 16 * f0) ^ ((r0 & 7) << 4));               // batch0
  const int lds1 = b1g * SXB + ((r1 * 128 + 16 * f1) ^ ((r1 & 7) << 4));
  const int lds2 = SXB + ((r2 * 128 + 16 * f2) ^ ((r2 & 7) << 4));
  const int lds3 = SXB + (((r3 & 63) * 128 + 16 * f3) ^ ((r3 & 7) << 4));

  const int tofs = t * 16;

  v4f accA[4][4], accB[4][4];
  #pragma unroll
  for (int i = 0; i < 4; ++i)
    #pragma unroll
    for (int j = 0; j < 4; ++j) {
      accA[i][j] = (v4f){0.f, 0.f, 0.f, 0.f};
      accB[i][j] = (v4f){0.f, 0.f, 0.f, 0.f};
    }

  // prologue: W chunk0 + X chunk0 in flight; commit chunk0 -> parity 0;
  // issue X chunk1; one barrier.
  v8s wA[8];
  ldw8(wA, wimg + tofs);
  float4 p0a = *(const float4*)(base0);
  float4 p0b = *(const float4*)(base0 + 16);
  float4 p1a = *(const float4*)(base1);
  float4 p1b = *(const float4*)(base1 + 16);
  float4 p2a = *(const float4*)(base2);
  float4 p2b = *(const float4*)(base2 + 16);
  float4 p3a = *(const float4*)(base3);
  float4 p3b = *(const float4*)(base3 + 16);

  commit8((char*)smem + lds0, p0a, p0b);
  commit8((char*)smem + lds1, p1a, p1b);
  commit8((char*)smem + lds2, p2a, p2b);
  if (act3) commit8((char*)smem + lds3, p3a, p3b);
  {
    p0a = *(const float4*)(base0 + 64);
    p0b = *(const float4*)(base0 + 64 + 16);
    p1a = *(const float4*)(base1 + 64);
    p1b = *(const float4*)(base1 + 64 + 16);
    p2a = *(const float4*)(base2 + 64);
    p2b = *(const float4*)(base2 + 64 + 16);
    p3a = *(const float4*)(base3 + 64);
    p3b = *(const float4*)(base3 + 64 + 16);
  }
  __builtin_amdgcn_sched_barrier(0);
  asm volatile("s_waitcnt lgkmcnt(0)" ::: "memory");
  __builtin_amdgcn_s_barrier();
  __builtin_amdgcn_sched_barrier(0);

  for (int kc = 0; kc < 12; ++kc) {
    const int pb = (kc & 1) * SXP;          // parity base for this chunk's MFMA
    const int cb = ((kc + 1) & 1) * SXP;    // parity base for next chunk's commit
    // ---- MFMA: batch0 then batch1 from sX[parity] (shared wA) ----
    #pragma unroll
    for (int ks = 0; ks < 2; ++ks) {
      const int off = ks * 64 + (q << 4);
      v8s af[4];
      #pragma unroll
      for (int mt = 0; mt < 4; ++mt) {
        int row = mt * 16 + lm;
        af[mt] = *(const v8s*)(smem + pb + ((row * 128 + off) ^ ((row & 7) << 4)));
      }
      #pragma unroll
      for (int mt = 0; mt < 4; ++mt)
        #pragma unroll
        for (int nt = 0; nt < 4; ++nt)
          accA[mt][nt] = __builtin_amdgcn_mfma_f32_16x16x32_bf16(af[mt], wA[2 * nt + ks], accA[mt][nt], 0, 0, 0);
    }
    #pragma unroll
    for (int ks = 0; ks < 2; ++ks) {
      const int off = ks * 64 + (q << 4);
      v8s af[4];
      #pragma unroll
      for (int mt = 0; mt < 4; ++mt) {
        int row = mt * 16 + lm;
        af[mt] = *(const v8s*)(smem + pb + SXB + ((row * 128 + off) ^ ((row & 7) << 4)));
      }
      #pragma unroll
      for (int mt = 0; mt < 4; ++mt)
        #pragma unroll
        for (int nt = 0; nt < 4; ++nt)
          accB[mt][nt] = __builtin_amdgcn_mfma_f32_16x16x32_bf16(af[mt], wA[2 * nt + ks], accB[mt][nt], 0, 0, 0);
    }
    if (kc < 11) {
      // reload W for chunk kc+1 (cover = commit stall + barrier)
      ldw8(wA, wimg + (kc + 1) * 32768 + tofs);
      // commit chunk kc+1 into the opposite parity (p-regs hold kc+1 data)
      commit8((char*)smem + cb + lds0, p0a, p0b);
      commit8((char*)smem + cb + lds1, p1a, p1b);
      commit8((char*)smem + cb + lds2, p2a, p2b);
      if (act3) commit8((char*)smem + cb + lds3, p3a, p3b);
      // issue X chunk kc+2
      if (kc < 10) {
        const int o = (kc + 2) * 64;
        p0a = *(const float4*)(base0 + o);
        p0b = *(const float4*)(base0 + o + 16);
        p1a = *(const float4*)(base1 + o);
        p1b = *(const float4*)(base1 + o + 16);
        p2a = *(const float4*)(base2 + o);
        p2b = *(const float4*)(base2 + o + 16);
        p3a = *(const float4*)(base3 + o);
        p3b = *(const float4*)(base3 + o + 16);
      }
    }
    // ONE barrier per chunk: commits visible; sX[pb] free for next commit
    __builtin_amdgcn_sched_barrier(0);
    asm volatile("s_waitcnt lgkmcnt(0)" ::: "memory");
    __builtin_amdgcn_s_barrier();
    __builtin_amdgcn_sched_barrier(0);
  }

  // issue Ahat fragment loads (latency hides under the pack below)
  const char* ahimg = wimg + AH_OFF;
  v8s afH[4][2], afL[4][2];
  #pragma unroll
  for (int mt = 0; mt < 4; ++mt)
    #pragma unroll
    for (int s2 = 0; s2 < 2; ++s2) {
      const int idx = ((mt * 2 + s2) * 256 + t) * 16;
      afH[mt][s2] = *(const v8s*)(ahimg + idx);
      afL[mt][s2] = *(const v8s*)(ahimg + 32768 + idx);
    }

  // -------- pack C1 accumulators to bf16 b-frags (halves reg footprint) --------
  v8s bA[2][4], bB[2][4];
  #pragma unroll
  for (int s2 = 0; s2 < 2; ++s2)
    #pragma unroll
    for (int nt = 0; nt < 4; ++nt) {
      v8s a, b;
      #pragma unroll
      for (int i = 0; i < 4; ++i) {
        a[i]     = (short)f2bf(accA[2 * s2][nt][i]);
        a[i + 4] = (short)f2bf(accA[2 * s2 + 1][nt][i]);
        b[i]     = (short)f2bf(accB[2 * s2][nt][i]);
        b[i + 4] = (short)f2bf(accB[2 * s2 + 1][nt][i]);
      }
      bA[s2][nt] = a; bB[s2][nt] = b;
    }

  float bi[4];
  #pragma unroll
  for (int nt = 0; nt < 4; ++nt) bi[nt] = b1v[64 * wv + 16 * nt + lm];

  // ====== AGG1 per batch: H1 = relu(Ahat @ C1 + b1) -> sH1_b (overlays sX) ======
  #pragma unroll
  for (int bb = 0; bb < 2; ++bb) {
    v4f ag[4][4];
    #pragma unroll
    for (int mt = 0; mt < 4; ++mt)
      #pragma unroll
      for (int nt = 0; nt < 4; ++nt)
        ag[mt][nt] = (v4f){bi[nt], bi[nt], bi[nt], bi[nt]};
    #pragma unroll
    for (int s2 = 0; s2 < 2; ++s2)
      #pragma unroll
      for (int nt = 0; nt < 4; ++nt) {
        v8s b = (bb == 0) ? bA[s2][nt] : bB[s2][nt];
        #pragma unroll
        for (int mt = 0; mt < 4; ++mt) {
          ag[mt][nt] = __builtin_amdgcn_mfma_f32_16x16x32_bf16(afL[mt][s2], b, ag[mt][nt], 0, 0, 0);
          ag[mt][nt] = __builtin_amdgcn_mfma_f32_16x16x32_bf16(afH[mt][s2], b, ag[mt][nt], 0, 0, 0);
        }
      }
    const int hbase = (bb == 0) ? SH1_0 : SH1_1;
    #pragma unroll
    for (int mt = 0; mt < 4; ++mt)
      #pragma unroll
      for (int nt = 0; nt < 4; ++nt) {
        int ch  = 64 * wv + 16 * nt + lm;
        int chb = 2 * permk(ch);
        #pragma unroll
        for (int r = 0; r < 4; ++r) {
          int row = 16 * mt + 4 * q + r;
          float hv = fmaxf(ag[mt][nt][r], 0.f);
          int byte = (row * 512 + chb) ^ ((row & 7) << 4);
          *(unsigned short*)(smem + hbase + byte) = f2bf(hv);
        }
      }
  }

  // issue W2 loads now (L2 latency hides under the barrier)
  const char* w2img = wimg + W1_IMG_BYTES;
  v8s w2c0[4], w2c1[4], w2c2[4], w2c3[4];
  ldw4(w2c0, w2img + tofs);
  ldw4(w2c1, w2img + 16384 + tofs);
  ldw4(w2c2, w2img + 2 * 16384 + tofs);
  ldw4(w2c3, w2img + 3 * 16384 + tofs);

  __builtin_amdgcn_sched_barrier(0);
  asm volatile("s_waitcnt lgkmcnt(0)" ::: "memory");
  __builtin_amdgcn_s_barrier();
  __builtin_amdgcn_sched_barrier(0);

  // ====== GEMM2 + AGG2 + pool per batch (w2c shared, no barriers) ======
  float b2i0 = b2v[32 * wv + lm];
  float b2i1 = b2v[32 * wv + 16 + lm];

  #pragma unroll
  for (int bb = 0; bb < 2; ++bb) {
    const int hbase = (bb == 0) ? SH1_0 : SH1_1;
    v4f acc3[4][2];
    #pragma unroll
    for (int i = 0; i < 4; ++i) {
      acc3[i][0] = (v4f){0.f, 0.f, 0.f, 0.f};
      acc3[i][1] = (v4f){0.f, 0.f, 0.f, 0.f};
    }
    #pragma unroll
    for (int kc = 0; kc < 4; ++kc)
      #pragma unroll
      for (int ks = 0; ks < 2; ++ks) {
        const int off = ks * 64 + (q << 4);
        v8s af[4];
        #pragma unroll
        for (int mt = 0; mt < 4; ++mt) {
          int row = mt * 16 + lm;
          int byte = (row * 512 + kc * 128 + off) ^ ((row & 7) << 4);
          af[mt] = *(const v8s*)(smem + hbase + byte);
        }
        const v8s* wc = (kc == 0) ? w2c0 : (kc == 1) ? w2c1 : (kc == 2) ? w2c2 : w2c3;
        #pragma unroll
        for (int mt = 0; mt < 4; ++mt)
          #pragma unroll
          for (int nt = 0; nt < 2; ++nt)
            acc3[mt][nt] = __builtin_amdgcn_mfma_f32_16x16x32_bf16(af[mt], wc[2 * nt + ks], acc3[mt][nt], 0, 0, 0);
      }
    // AGG2
    v4f a2[4][2];
    #pragma unroll
    for (int mt = 0; mt < 4; ++mt) {
      a2[mt][0] = (v4f){b2i0, b2i0, b2i0, b2i0};
      a2[mt][1] = (v4f){b2i1, b2i1, b2i1, b2i1};
    }
    #pragma unroll
    for (int s2 = 0; s2 < 2; ++s2)
      #pragma unroll
      for (int nt = 0; nt < 2; ++nt) {
        v8s b;
        #pragma unroll
        for (int i = 0; i < 4; ++i) {
          b[i]     = (short)f2bf(acc3[2 * s2][nt][i]);
          b[i + 4] = (short)f2bf(acc3[2 * s2 + 1][nt][i]);
        }
        #pragma unroll
        for (int mt = 0; mt < 4; ++mt) {
          a2[mt][nt] = __builtin_amdgcn_mfma_f32_16x16x32_bf16(afL[mt][s2], b, a2[mt][nt], 0, 0, 0);
          a2[mt][nt] = __builtin_amdgcn_mfma_f32_16x16x32_bf16(afH[mt][s2], b, a2[mt][nt], 0, 0, 0);
        }
      }
    // pool: rows 0..47 (mt<3) + row 48 (q==0, r==0)
    float ps0 = 0.f, ps1 = 0.f;
    #pragma unroll
    for (int mt = 0; mt < 3; ++mt)
      #pragma unroll
      for (int r = 0; r < 4; ++r) {
        ps0 += fmaxf(a2[mt][0][r], 0.f);
        ps1 += fmaxf(a2[mt][1][r], 0.f);
      }
    if (q == 0) {
      ps0 += fmaxf(a2[3][0][0], 0.f);
      ps1 += fmaxf(a2[3][1][0], 0.f);
    }
    ps0 += __shfl_xor(ps0, 16); ps0 += __shfl_xor(ps0, 32);
    ps1 += __shfl_xor(ps1, 16); ps1 += __shfl_xor(ps1, 32);
    float* spool = (float*)(smem + ((bb == 0) ? SPOOL0 : SPOOL1));
    if (q == 0) {
      spool[32 * wv + lm]      = ps0 * (1.0f / 49.0f);
      spool[32 * wv + 16 + lm] = ps1 * (1.0f / 49.0f);
    }
  }
  __syncthreads();
  // fc: wave w handles batch (w>>1), channels {2*(w&1), 2*(w&1)+1}; lane-parallel over d
  {
    const int bb = wv >> 1;
    const int c0 = (wv & 1) * 2;
    const float* spool = (const float*)(smem + (bb ? SPOOL1 : SPOOL0));
    float d0 = spool[ln];
    float d1 = spool[ln + 64];
    float a0 = d0 * fcWv[ln * 4 + c0]     + d1 * fcWv[(ln + 64) * 4 + c0];
    float a1 = d0 * fcWv[ln * 4 + c0 + 1] + d1 * fcWv[(ln + 64) * 4 + c0 + 1];
    #pragma unroll
    for (int s = 32; s; s >>= 1) { a0 += __shfl_xor(a0, s); a1 += __shfl_xor(a1, s); }
    if (ln == 0) {
      out[(size_t)(2 * blockIdx.x + bb) * 4 + c0]     = a0 + fcbv[c0];
      out[(size_t)(2 * blockIdx.x + bb) * 4 + c0 + 1] = a1 + fcbv[c0 + 1];
    }
  }
}

// ===================== fallback (round-1 kernel, no d_ws) =====================
#define OFF_SX    0
#define OFF_SWT   8192
#define OFF_SC    0
#define OFF_SWT2  0
#define OFF_SPOOL 25872
#define OFF_SPF   30096
#define OFF_SH1   40960
#define OFF_NBRW  73728
#define OFF_NBRI  75492
#define OFF_B1    77256
#define OFF_B2    78280
#define OFF_FCW   78792
#define OFF_FCB   80840
#define SMEM_SZ   80856

__global__ __launch_bounds__(256, 2) void gcn_fused_fb(
    const float* __restrict__ X, const float* __restrict__ W1,
    const float* __restrict__ b1v, const float* __restrict__ W2,
    const float* __restrict__ b2v, const float* __restrict__ fcWv,
    const float* __restrict__ fcbv, float* __restrict__ out)
{
  __shared__ __align__(16) char smem[SMEM_SZ];
  const int t  = threadIdx.x;
  const int wv = t >> 6;
  const int ln = t & 63;
  const int q  = ln >> 4;
  const int lm = ln & 15;

  float* nbrW = (float*)(smem + OFF_NBRW);
  int*   nbrI = (int*)  (smem + OFF_NBRI);
  float* b1s  = (float*)(smem + OFF_B1);
  float* b2s  = (float*)(smem + OFF_B2);
  float* fcWs = (float*)(smem + OFF_FCW);
  float* fcbs = (float*)(smem + OFF_FCB);
  float* sC   = (float*)(smem + OFF_SC);

  if (t < D1) b1s[t] = b1v[t];
  if (t < D2) b2s[t] = b2v[t];
  fcWs[t]       = fcWv[t];
  fcWs[t + 256] = fcWv[t + 256];
  if (t < 4) fcbs[t] = fcbv[t];
  if (t < NN) {
    int y = t / 7, x = t % 7;
    float rm = rsqrtf((float)((1 + (y > 0) + (y < 6)) * (1 + (x > 0) + (x < 6))) + 1.0f);
    int cnt = 0;
    for (int dy = -1; dy <= 1; ++dy)
      for (int dx = -1; dx <= 1; ++dx) {
        int ny = y + dy, nx = x + dx;
        if (ny >= 0 && ny < 7 && nx >= 0 && nx < 7) {
          int n = ny * 7 + nx;
          float rn = rsqrtf((float)((1 + (ny > 0) + (ny < 6)) * (1 + (nx > 0) + (nx < 6))) + 1.0f);
          nbrW[t * 9 + cnt] = ((n == t) ? 2.0f : 1.0f) * rm * rn;
          nbrI[t * 9 + cnt] = n;
          ++cnt;
        }
      }
    for (; cnt < 9; ++cnt) { nbrW[t * 9 + cnt] = 0.0f; nbrI[t * 9 + cnt] = 0; }
  }
  __syncthreads();

  const float* Xb = X + (size_t)blockIdx.x * (NN * D0);
  v4f acc[4][4];
  #pragma unroll
  for (int i = 0; i < 4; ++i)
    #pragma unroll
    for (int j = 0; j < 4; ++j)
      acc[i][j] = (v4f){0.f, 0.f, 0.f, 0.f};

  for (int kc = 0; kc < 12; ++kc) {
    __syncthreads();
    #pragma unroll
    for (int p = 0; p < 4; ++p) {
      int idx = t + 256 * p;
      int row = idx >> 4;
      int k4  = (idx & 15) << 2;
      float4 v = {0.f, 0.f, 0.f, 0.f};
      if (row < NN) v = *(const float4*)(Xb + row * D0 + kc * 64 + k4);
      ushort4 s;
      s.x = f2bf(v.x); s.y = f2bf(v.y); s.z = f2bf(v.z); s.w = f2bf(v.w);
      int byte = row * 128 + 2 * permk(k4);
      byte ^= (row & 7) << 4;
      *(ushort4*)(smem + OFF_SX + byte) = s;
    }
    #pragma unroll
    for (int p = 0; p < 4; ++p) {
      int bid2 = t + 256 * p;
      int k0 = (bid2 & 15) << 2;
      int n0 = (bid2 >> 4) << 2;
      const float* wp = W1 + (size_t)(kc * 64 + k0) * D1 + n0;
      float4 r0 = *(const float4*)(wp);
      float4 r1 = *(const float4*)(wp + D1);
      float4 r2 = *(const float4*)(wp + 2 * D1);
      float4 r3 = *(const float4*)(wp + 3 * D1);
      int kb = 2 * permk(k0);
      ushort4 s; int byte;
      s.x = f2bf(r0.x); s.y = f2bf(r1.x); s.z = f2bf(r2.x); s.w = f2bf(r3.x);
      byte = (n0 + 0) * 128 + kb; byte ^= ((n0 + 0) & 7) << 4;
      *(ushort4*)(smem + OFF_SWT + byte) = s;
      s.x = f2bf(r0.y); s.y = f2bf(r1.y); s.z = f2bf(r2.y); s.w = f2bf(r3.y);
      byte = (n0 + 1) * 128 + kb; byte ^= ((n0 + 1) & 7) << 4;
      *(ushort4*)(smem + OFF_SWT + byte) = s;
      s.x = f2bf(r0.z); s.y = f2bf(r1.z); s.z = f2bf(r2.z); s.w = f2bf(r3.z);
      byte = (n0 + 2) * 128 + kb; byte ^= ((n0 + 2) & 7) << 4;
      *(ushort4*)(smem + OFF_SWT + byte) = s;
      s.x = f2bf(r0.w); s.y = f2bf(r1.w); s.z = f2bf(r2.w); s.w = f2bf(r3.w);
      byte = (n0 + 3) * 128 + kb; byte ^= ((n0 + 3) & 7) << 4;
      *(ushort4*)(smem + OFF_SWT + byte) = s;
    }
    __syncthreads();
    #pragma unroll
    for (int ks = 0; ks < 2; ++ks) {
      int off = ks * 64 + (q << 4);
      v8s af[4], bf[4];
      #pragma unroll
      for (int mt = 0; mt < 4; ++mt) {
        int row = mt * 16 + lm;
        int byte = row * 128 + off; byte ^= (row & 7) << 4;
        af[mt] = *(const v8s*)(smem + OFF_SX + byte);
      }
      #pragma unroll
      for (int nt = 0; nt < 4; ++nt) {
        int n = (wv * 4 + nt) * 16 + lm;
        int byte = n * 128 + off; byte ^= (n & 7) << 4;
        bf[nt] = *(const v8s*)(smem + OFF_SWT + byte);
      }
      #pragma unroll
      for (int mt = 0; mt < 4; ++mt)
        #pragma unroll
        for (int nt = 0; nt < 4; ++nt)
          acc[mt][nt] = __builtin_amdgcn_mfma_f32_16x16x32_bf16(af[mt], bf[nt], acc[mt][nt], 0, 0, 0);
    }
  }

  #pragma unroll
  for (int h = 0; h < 2; ++h) {
    __syncthreads();
    if ((wv >> 1) == h) {
      #pragma unroll
      for (int mt = 0; mt < 4; ++mt) {
        int rbase = mt * 16 + (q << 2);
        #pragma unroll
        for (int nt = 0; nt < 4; ++nt) {
          int c = ((wv & 1) * 4 + nt) * 16 + lm;
          #pragma unroll
          for (int r = 0; r < 4; ++r) {
            int row = rbase + r;
            if (row < NN) sC[row * 132 + c] = acc[mt][nt][r];
          }
        }
      }
    }
    __syncthreads();
    for (int p = 0; p < 7; ++p) {
      int idx = t + 256 * p;
      if (idx < NN * 32) {
        int m  = idx >> 5;
        int d4 = (idx & 31) << 2;
        int dg = h * 128 + d4;
        float a0 = b1s[dg], a1 = b1s[dg + 1], a2 = b1s[dg + 2], a3 = b1s[dg + 3];
        #pragma unroll
        for (int e = 0; e < 9; ++e) {
          float w = nbrW[m * 9 + e];
          int   n = nbrI[m * 9 + e];
          float4 cv = *(const float4*)(sC + n * 132 + d4);
          a0 += w * cv.x; a1 += w * cv.y; a2 += w * cv.z; a3 += w * cv.w;
        }
        a0 = fmaxf(a0, 0.f); a1 = fmaxf(a1, 0.f); a2 = fmaxf(a2, 0.f); a3 = fmaxf(a3, 0.f);
        ushort4 s; s.x = f2bf(a0); s.y = f2bf(a1); s.z = f2bf(a2); s.w = f2bf(a3);
        int byte = m * 512 + 2 * permk(dg);
        byte ^= (m & 7) << 4;
        *(ushort4*)(smem + OFF_SH1 + byte) = s;
      }
    }
  }

  v4f acc2[4][2];
  #pragma unroll
  for (int i = 0; i < 4; ++i) { acc2[i][0] = (v4f){0.f,0.f,0.f,0.f}; acc2[i][1] = (v4f){0.f,0.f,0.f,0.f}; }

  for (int kc = 0; kc < 4; ++kc) {
    __syncthreads();
    #pragma unroll
    for (int p = 0; p < 2; ++p) {
      int bid2 = t + 256 * p;
      int k0 = (bid2 & 15) << 2;
      int n0 = (bid2 >> 4) << 2;
      const float* wp = W2 + (size_t)(kc * 64 + k0) * D2 + n0;
      float4 r0 = *(const float4*)(wp);
      float4 r1 = *(const float4*)(wp + D2);
      float4 r2 = *(const float4*)(wp + 2 * D2);
      float4 r3 = *(const float4*)(wp + 3 * D2);
      int kb = 2 * permk(k0);
      ushort4 s; int byte;
      s.x = f2bf(r0.x); s.y = f2bf(r1.x); s.z = f2bf(r2.x); s.w = f2bf(r3.x);
      byte = (n0 + 0) * 128 + kb; byte ^= ((n0 + 0) & 7) << 4;
      *(ushort4*)(smem + OFF_SWT2 + byte) = s;
      s.x = f2bf(r0.y); s.y = f2bf(r1.y); s.z = f2bf(r2.y); s.w = f2bf(r3.y);
      byte = (n0 + 1) * 128 + kb; byte ^= ((n0 + 1) & 7) << 4;
      *(ushort4*)(smem + OFF_SWT2 + byte) = s;
      s.x = f2bf(r0.z); s.y = f2bf(r1.z); s.z = f2bf(r2.z); s.w = f2bf(r3.z);
      byte = (n0 + 2) * 128 + kb; byte ^= ((n0 + 2) & 7) << 4;
      *(ushort4*)(smem + OFF_SWT2 + byte) = s;
      s.x = f2bf(r0.w); s.y = f2bf(r1.w); s.z = f2bf(r2.w); s.w = f2bf(r3.w);
      byte = (n0 + 3) * 128 + kb; byte ^= ((n0 + 3) & 7) << 4;
      *(ushort4*)(smem + OFF_SWT2 + byte) = s;
    }
    __syncthreads();
    #pragma unroll
    for (int ks = 0; ks < 2; ++ks) {
      int off = ks * 64 + (q << 4);
      v8s af[4], bf2[2];
      #pragma unroll
      for (int mt = 0; mt < 4; ++mt) {
        int row = mt * 16 + lm;
        int byte = row * 512 + kc * 128 + off; byte ^= (row & 7) << 4;
        af[mt] = *(const v8s*)(smem + OFF_SH1 + byte);
      }
      #pragma unroll
      for (int nt = 0; nt < 2; ++nt) {
        int n = (wv * 2 + nt) * 16 + lm;
        int byte = n * 128 + off; byte ^= (n & 7) << 4;
        bf2[nt] = *(const v8s*)(smem + OFF_SWT2 + byte);
      }
      #pragma unroll
      for (int mt = 0; mt < 4; ++mt)
        #pragma unroll
        for (int nt = 0; nt < 2; ++nt)
          acc2[mt][nt] = __builtin_amdgcn_mfma_f32_16x16x32_bf16(af[mt], bf2[nt], acc2[mt][nt], 0, 0, 0);
    }
  }

  __syncthreads();
  #pragma unroll
  for (int mt = 0; mt < 4; ++mt) {
    int rbase = mt * 16 + (q << 2);
    #pragma unroll
    for (int nt = 0; nt < 2; ++nt) {
      int c = (wv * 2 + nt) * 16 + lm;
      #pragma unroll
      for (int r = 0; r < 4; ++r) {
        int row = rbase + r;
        if (row < NN) sC[row * 132 + c] = acc2[mt][nt][r];
      }
    }
  }
  __syncthreads();
  {
    int d4 = (t & 31) << 2;
    int g  = t >> 5;
    float p0 = 0.f, p1 = 0.f, p2 = 0.f, p3 = 0.f;
    int m0 = g * 7, m1 = (g * 7 + 7 < NN) ? (g * 7 + 7) : NN;
    for (int m = m0; m < m1; ++m) {
      float a0 = b2s[d4], a1 = b2s[d4 + 1], a2 = b2s[d4 + 2], a3 = b2s[d4 + 3];
      #pragma unroll
      for (int e = 0; e < 9; ++e) {
        float w = nbrW[m * 9 + e];
        int   n = nbrI[m * 9 + e];
        float4 cv = *(const float4*)(sC + n * 132 + d4);
        a0 += w * cv.x; a1 += w * cv.y; a2 += w * cv.z; a3 += w * cv.w;
      }
      p0 += fmaxf(a0, 0.f); p1 += fmaxf(a1, 0.f); p2 += fmaxf(a2, 0.f); p3 += fmaxf(a3, 0.f);
    }
    float* sp = (float*)(smem + OFF_SPOOL) + g * 132 + d4;
    sp[0] = p0; sp[1] = p1; sp[2] = p2; sp[3] = p3;
  }
  __syncthreads();
  if (t < D2) {
    const float* sp = (const float*)(smem + OFF_SPOOL);
    float s = 0.f;
    #pragma unroll
    for (int g = 0; g < 8; ++g) s += sp[g * 132 + t];
    ((float*)(smem + OFF_SPF))[t] = s * (1.0f / 49.0f);
  }
  __syncthreads();
  if (t < 4) {
    const float* pf = (const float*)(smem + OFF_SPF);
    float a = fcbs[t];
    for (int d = 0; d < D2; ++d) a += pf[d] * fcWs[d * 4 + t];
    out[(size_t)blockIdx.x * 4 + t] = a;
  }
}

extern "C" void kernel_launch(void* const* d_in, const int* in_sizes, int n_in,
                              void* d_out, int out_size, void* d_ws, size_t ws_size,
                              hipStream_t stream) {
  const float* X   = (const float*)d_in[0];
  const float* W1  = (const float*)d_in[1];
  const float* b1  = (const float*)d_in[2];
  const float* W2  = (const float*)d_in[3];
  const float* b2  = (const float*)d_in[4];
  const float* fcW = (const float*)d_in[5];
  const float* fcb = (const float*)d_in[6];
  float* out = (float*)d_out;
  int B = in_sizes[0] / (NN * D0);   // 4096
  if (d_ws != nullptr && ws_size >= (size_t)WS_NEEDED && (B % 2) == 0) {
    prep_w<<<120, 256, 0, stream>>>(W1, W2, (char*)d_ws);
    gcn_fused11<<<B / 2, 256, 0, stream>>>(X, (const char*)d_ws, b1, b2, fcW, fcb, out);
  } else {
    gcn_fused_fb<<<B, 256, 0, stream>>>(X, W1, b1, W2, b2, fcW, fcb, out);
  }
}